// Round 5
// baseline (161815.979 us; speedup 1.0000x reference)
//
#include <hip/hip_runtime.h>

// ---------------- problem constants ----------------
#define PL 400
#define QL 60
#define BB 128
#define EE 512
#define HH 256
#define DD 1024
#define G3 768
#define NBLK 256
#define NTHR 512
#define LDK 72   // padded K stride (shorts) for LDS tiles

typedef __attribute__((ext_vector_type(8))) short bfrag;
typedef __attribute__((ext_vector_type(4))) float facc;

// ---------------- bf16 / math helpers ----------------
__device__ __forceinline__ unsigned short f2bf(float x) {
  unsigned u = __float_as_uint(x);
  return (unsigned short)((u + 0x7fffu + ((u >> 16) & 1u)) >> 16);
}
__device__ __forceinline__ float bf2f(unsigned short h) {
  return __uint_as_float(((unsigned)h) << 16);
}
__device__ __forceinline__ void split_bf(float x, unsigned short& hi, unsigned short& lo) {
  hi = f2bf(x);
  lo = f2bf(x - bf2f(hi));
}
__device__ __forceinline__ unsigned packf(float x) {
  unsigned short hi, lo;
  split_bf(x, hi, lo);
  return ((unsigned)hi << 16) | lo;
}
__device__ __forceinline__ float unpk(unsigned p) {
  return bf2f((unsigned short)(p >> 16)) + bf2f((unsigned short)(p & 0xffffu));
}
__device__ __forceinline__ float sigm(float x) {
  return __builtin_amdgcn_rcpf(1.f + __expf(-x));
}
__device__ __forceinline__ float ftanh(float x) {
  float xc = fminf(fmaxf(x, -10.f), 10.f);
  float t = __expf(2.f * xc);
  return (t - 1.f) * __builtin_amdgcn_rcpf(t + 1.f);
}

// ---------------- agent-scope relaxed atomics (MALL-coherent) ----------------
__device__ __forceinline__ float ald(const float* p) {
  return __hip_atomic_load((float*)p, __ATOMIC_RELAXED, __HIP_MEMORY_SCOPE_AGENT);
}
__device__ __forceinline__ void ast(float* p, float v) {
  __hip_atomic_store(p, v, __ATOMIC_RELAXED, __HIP_MEMORY_SCOPE_AGENT);
}
__device__ __forceinline__ unsigned aldu(const unsigned* p) {
  return __hip_atomic_load((unsigned*)p, __ATOMIC_RELAXED, __HIP_MEMORY_SCOPE_AGENT);
}
__device__ __forceinline__ void astu(unsigned* p, unsigned v) {
  __hip_atomic_store(p, v, __ATOMIC_RELAXED, __HIP_MEMORY_SCOPE_AGENT);
}

// ---------------- ws layout ----------------
// fp32 region
constexpr size_t SZ_QT  = (size_t)2 * QL * BB * HH;
constexpr size_t SZ_PT  = (size_t)2 * PL * BB * HH;
constexpr size_t SZ_GHP = (size_t)2 * BB * G3;     // gh final
constexpr size_t SZ_GIF = (size_t)2 * BB * G3;     // gi final
constexpr size_t SZ_WST = (size_t)2 * HH * HH;     // Ws transposed
constexpr size_t OFF_QT  = 0;
constexpr size_t OFF_PT  = OFF_QT + SZ_QT;
constexpr size_t OFF_GHP = OFF_PT + SZ_PT;
constexpr size_t OFF_GIF = OFF_GHP + SZ_GHP;
constexpr size_t OFF_WST = OFF_GIF + SZ_GIF;
constexpr size_t F32_TOT = OFF_WST + SZ_WST;
// uint region (packed hi/lo bf16)
constexpr size_t UOFF_ATTP  = 0;                               // [d][b][512]
constexpr size_t UOFF_XPACK = UOFF_ATTP + (size_t)2 * BB * EE; // [d][b][1024]
constexpr size_t UOFF_HPACK = UOFF_XPACK + (size_t)2 * BB * DD;// [d][b][256]
constexpr size_t U_TOT      = UOFF_HPACK + (size_t)2 * BB * HH;
// bf16 (ushort) weight region
constexpr size_t HSZ_WQT = (size_t)2 * HH * EE;
constexpr size_t HSZ_GW  = (size_t)2 * DD * DD;
constexpr size_t HSZ_WIH = (size_t)2 * G3 * DD;
constexpr size_t HSZ_WHH = (size_t)2 * G3 * HH;
constexpr size_t HOFF_WQTH = 0;
constexpr size_t HOFF_WQTL = HOFF_WQTH + HSZ_WQT;
constexpr size_t HOFF_WPTH = HOFF_WQTL + HSZ_WQT;
constexpr size_t HOFF_WPTL = HOFF_WPTH + HSZ_WQT;
constexpr size_t HOFF_GWH  = HOFF_WPTL + HSZ_WQT;
constexpr size_t HOFF_GWL  = HOFF_GWH + HSZ_GW;
constexpr size_t HOFF_WIHH = HOFF_GWL + HSZ_GW;
constexpr size_t HOFF_WIHL = HOFF_WIHH + HSZ_WIH;
constexpr size_t HOFF_WHHH = HOFF_WIHL + HSZ_WIH;
constexpr size_t HOFF_WHHL = HOFF_WHHH + HSZ_WHH;
constexpr size_t H_TOT     = HOFF_WHHL + HSZ_WHH;

// ---------------- grid barrier: flat all-poll, fence-free ----------------
__device__ __forceinline__ void gbar(unsigned* slots, unsigned gen) {
  asm volatile("" ::: "memory");
  __syncthreads();  // drains vmcnt for all waves of this block (release point)
  if (threadIdx.x == 0)
    __hip_atomic_store(&slots[blockIdx.x], gen, __ATOMIC_RELAXED, __HIP_MEMORY_SCOPE_AGENT);
  if (threadIdx.x < NBLK) {
    unsigned sp = 0;
    while (__hip_atomic_load(&slots[threadIdx.x], __ATOMIC_RELAXED, __HIP_MEMORY_SCOPE_AGENT) < gen) {
      __builtin_amdgcn_s_sleep(1);
      if (++sp > (1u << 26)) break;  // hang bailout
    }
  }
  __syncthreads();
  asm volatile("" ::: "memory");
}

// ---------------- unified MFMA GEMM tile ----------------
// M=128 (batch rows). NT = 128 or 64 output cols. K = NCH*64 from kbase.
// A source per chunk (uniform): kk < SPLITK -> fp32 a32[r*a32s + kk] (split hi/lo);
//                               else packed apk[r*apks + kk - SPLITK] (unpack).
// Cross-chunk register prefetch of the 4B A-words.
// BG: 0 = B resident in warea (chunk-major), 1 = stream hi/lo from global,
//     2 = stream single-bf16 from global.
// EPI: 0 = plain fp32 store, 1 = atomic fp32 store,
//      2 = gate: x = u * sigm(acc + gb), store packed to dstu.
template <int NT, bool BSPLIT, int BG, int SPLITK, int EPI, int NCH>
__device__ void gemm_t(unsigned short* sAh, unsigned short* sAl, unsigned short* warea,
                       const float* a32, int a32s,
                       const unsigned* apk, int apks,
                       const unsigned short* bh_g, const unsigned short* bl_g, int bstride,
                       float* dstf, unsigned* dstu, int dstride,
                       const float* uf_src, const unsigned* up_src, int ustride,
                       const float* gbv, int kbase) {
  const int tid = threadIdx.x;
  const int lane = tid & 63;
  const int w = tid >> 6;
  constexpr int FM = (NT == 128) ? 4 : 2;
  constexpr int FN = 2;
  const int wm = (NT == 128) ? ((w >> 2) << 6) : ((w >> 1) << 5);
  const int wn = (NT == 128) ? ((w & 3) << 5) : ((w & 1) << 5);
  const int lr = lane & 15;
  const int lk = (lane >> 4) << 3;

  unsigned short* wh = warea;
  unsigned short* wl = (BG == 0) ? (warea + NCH * NT * LDK) : (warea + NT * LDK);

  const facc fz = {0.f, 0.f, 0.f, 0.f};
  facc acc[FM][FN];
#pragma unroll
  for (int i = 0; i < FM; i++)
#pragma unroll
    for (int j = 0; j < FN; j++) acc[i][j] = fz;

  unsigned pva[16], pvb[16];
  {
    const int kk0 = kbase;
#pragma unroll
    for (int ii = 0; ii < 16; ii++) {
      int r = ii * 8 + w;
      if (kk0 < SPLITK)
        pva[ii] = __float_as_uint(a32[(size_t)r * a32s + kk0 + lane]);
      else
        pva[ii] = aldu(&apk[(size_t)r * apks + kk0 - SPLITK + lane]);
    }
  }

#pragma unroll
  for (int ch = 0; ch < NCH; ++ch) {
    const int kk0 = kbase + (ch << 6);
    unsigned* cur = (ch & 1) ? pvb : pva;
    unsigned* nxt = (ch & 1) ? pva : pvb;
    // ---- B stage FIRST (its vmcnt wait must not strand the A-prefetch) ----
    if constexpr (BG != 0) {
#pragma unroll
      for (int i2 = 0; i2 < NT * 64 / NTHR; i2++) {
        int i = i2 * NTHR + tid;
        int n = i >> 6, k = i & 63;
        wh[n * LDK + k] = bh_g[(size_t)n * bstride + kk0 + k];
        if constexpr (BG == 1) wl[n * LDK + k] = bl_g[(size_t)n * bstride + kk0 + k];
      }
    }
    // ---- A prefetch next chunk (stays in flight across the barrier) ----
    if (ch + 1 < NCH) {
      const int kk1 = kk0 + 64;
#pragma unroll
      for (int ii = 0; ii < 16; ii++) {
        int r = ii * 8 + w;
        if (kk1 < SPLITK)
          nxt[ii] = __float_as_uint(a32[(size_t)r * a32s + kk1 + lane]);
        else
          nxt[ii] = aldu(&apk[(size_t)r * apks + kk1 - SPLITK + lane]);
      }
    }
    // ---- A convert + LDS store (regs from previous prefetch) ----
    const bool f32c = (kk0 < SPLITK);
#pragma unroll
    for (int ii = 0; ii < 16; ii++) {
      int r = ii * 8 + w;
      unsigned p = cur[ii];
      unsigned short uh, ul;
      if (f32c) split_bf(__uint_as_float(p), uh, ul);
      else { uh = (unsigned short)(p >> 16); ul = (unsigned short)(p & 0xffffu); }
      sAh[r * LDK + lane] = uh;
      sAl[r * LDK + lane] = ul;
    }
    asm volatile("s_waitcnt lgkmcnt(0)" ::: "memory");
    __builtin_amdgcn_s_barrier();
    __builtin_amdgcn_sched_barrier(0);

    const int wch = (BG == 0) ? ch : 0;
#pragma unroll
    for (int k32 = 0; k32 < 64; k32 += 32) {
      bfrag ah[FM], al_[FM], bhf[FN], blf[FN];
#pragma unroll
      for (int f = 0; f < FM; f++) {
        const int ao = (wm + (f << 4) + lr) * LDK + k32 + lk;
        ah[f]  = *(const bfrag*)&sAh[ao];
        al_[f] = *(const bfrag*)&sAl[ao];
      }
#pragma unroll
      for (int f = 0; f < FN; f++) {
        const int bo = (wch * NT + wn + (f << 4) + lr) * LDK + k32 + lk;
        bhf[f] = *(const bfrag*)&wh[bo];
        if constexpr (BSPLIT) blf[f] = *(const bfrag*)&wl[bo];
      }
#pragma unroll
      for (int i = 0; i < FM; i++)
#pragma unroll
        for (int j = 0; j < FN; j++) {
          acc[i][j] = __builtin_amdgcn_mfma_f32_16x16x32_bf16(al_[i], bhf[j], acc[i][j], 0, 0, 0);
          if constexpr (BSPLIT)
            acc[i][j] = __builtin_amdgcn_mfma_f32_16x16x32_bf16(ah[i], blf[j], acc[i][j], 0, 0, 0);
          acc[i][j] = __builtin_amdgcn_mfma_f32_16x16x32_bf16(ah[i], bhf[j], acc[i][j], 0, 0, 0);
        }
    }
    __builtin_amdgcn_sched_barrier(0);
    __builtin_amdgcn_s_barrier();
    __builtin_amdgcn_sched_barrier(0);
  }
  // ---- epilogue ----
  const int orow = (lane >> 4) << 2;
  const int ocol = lane & 15;
#pragma unroll
  for (int i = 0; i < FM; i++)
#pragma unroll
    for (int j = 0; j < FN; j++)
#pragma unroll
      for (int q = 0; q < 4; q++) {
        const int row = wm + (i << 4) + orow + q;
        const int col = wn + (j << 4) + ocol;
        float val = acc[i][j][q];
        if constexpr (EPI == 0) {
          dstf[(size_t)row * dstride + col] = val;
        } else if constexpr (EPI == 1) {
          ast(&dstf[(size_t)row * dstride + col], val);
        } else {
          float uv = uf_src ? uf_src[(size_t)row * ustride + col]
                            : unpk(aldu(&up_src[(size_t)row * ustride + col]));
          float x = uv * sigm(val + gbv[col]);
          astu(&dstu[(size_t)row * dstride + col], packf(x));
        }
      }
}

// ---------------- setup kernels ----------------
__global__ void __launch_bounds__(256) k_transpose_qp(
    const float* __restrict__ Wq, const float* __restrict__ Wp,
    unsigned short* __restrict__ wqth, unsigned short* __restrict__ wqtl,
    unsigned short* __restrict__ wpth, unsigned short* __restrict__ wptl) {
  __shared__ float tile[64 * 65];
  const int blk = blockIdx.x;
  const int mat = blk >> 6;
  const int rem = blk & 63;
  const int d = rem >> 5;
  const int rem2 = rem & 31;
  const int kt = rem2 >> 2;
  const int nt = rem2 & 3;
  const float* src = mat ? Wp : Wq;
  unsigned short* dh = mat ? wpth : wqth;
  unsigned short* dl = mat ? wptl : wqtl;
  const int tid = threadIdx.x;
  for (int i = tid; i < 4096; i += 256) {
    int kr = i >> 6, nc = i & 63;
    tile[kr * 65 + nc] = src[((size_t)d * EE + kt * 64 + kr) * HH + nt * 64 + nc];
  }
  __syncthreads();
  for (int i = tid; i < 4096; i += 256) {
    int n = i >> 6, k = i & 63;
    unsigned short hi, lo;
    split_bf(tile[k * 65 + n], hi, lo);
    size_t o = ((size_t)d * HH + nt * 64 + n) * EE + kt * 64 + k;
    dh[o] = hi; dl[o] = lo;
  }
}

__global__ void __launch_bounds__(256) k_split_w(
    const float* __restrict__ gw, const float* __restrict__ wih, const float* __restrict__ whh,
    unsigned short* __restrict__ gwh, unsigned short* __restrict__ gwl,
    unsigned short* __restrict__ wihh, unsigned short* __restrict__ wihl,
    unsigned short* __restrict__ whhh, unsigned short* __restrict__ whhl) {
  const size_t N1 = HSZ_GW, N2 = HSZ_WIH, N3 = HSZ_WHH;
  for (size_t i = (size_t)blockIdx.x * 256 + threadIdx.x; i < N1 + N2 + N3;
       i += (size_t)gridDim.x * 256) {
    float x; unsigned short *ph, *pl; size_t o;
    if (i < N1)           { o = i;           x = gw[o];  ph = gwh;  pl = gwl; }
    else if (i < N1 + N2) { o = i - N1;      x = wih[o]; ph = wihh; pl = wihl; }
    else                  { o = i - N1 - N2; x = whh[o]; ph = whhh; pl = whhl; }
    unsigned short hi, lo;
    split_bf(x, hi, lo);
    ph[o] = hi; pl[o] = lo;
  }
}

__global__ void __launch_bounds__(256) k_wst(const float* __restrict__ Ws,
                                             float* __restrict__ wst) {
  size_t i = (size_t)blockIdx.x * 256 + threadIdx.x;
  if (i >= SZ_WST) return;
  int d = (int)(i >> 16);
  int j = (int)((i >> 8) & 255);
  int k = (int)(i & 255);
  wst[i] = Ws[((size_t)d * HH + k) * HH + j];
}

// ---------------- the persistent kernel ----------------
__global__ void __launch_bounds__(NTHR, 1) pe_main(
    const float* __restrict__ qin, const float* __restrict__ pin,
    const unsigned char* __restrict__ qmask,
    const float* __restrict__ vvec, const float* __restrict__ gateb,
    const float* __restrict__ bih, const float* __restrict__ bhh,
    float* __restrict__ out,
    float* __restrict__ fws, unsigned* __restrict__ upck,
    unsigned short* __restrict__ hws, unsigned* __restrict__ bar) {
  __shared__ __align__(16) unsigned short smem[55296];  // 110.6 KB
  unsigned short* sAh = smem;            // 9216 shorts
  unsigned short* sAl = smem + 9216;     // 9216 shorts
  unsigned short* warea = smem + 18432;  // 36864 shorts (stream staging / gh resident)
  float* fsm = (float*)smem;             // phase A / C2 scratch (aliases sAh/sAl)

  float* qt   = fws + OFF_QT;
  float* pt   = fws + OFF_PT;
  float* ghp  = fws + OFF_GHP;
  float* gif  = fws + OFF_GIF;
  float* wst  = fws + OFF_WST;
  unsigned* attp  = upck + UOFF_ATTP;
  unsigned* xpack = upck + UOFF_XPACK;
  unsigned* hpack = upck + UOFF_HPACK;
  unsigned short* wqth = hws + HOFF_WQTH;
  unsigned short* wqtl = hws + HOFF_WQTL;
  unsigned short* wpth = hws + HOFF_WPTH;
  unsigned short* wptl = hws + HOFF_WPTL;
  unsigned short* gwh  = hws + HOFF_GWH;
  unsigned short* wihh = hws + HOFF_WIHH;
  unsigned short* wihl = hws + HOFF_WIHL;
  unsigned short* whhh = hws + HOFF_WHHH;
  unsigned short* whhl = hws + HOFF_WHHL;

  const int blk = blockIdx.x;
  const int tid = threadIdx.x;
  const int lane = tid & 63;
  const int w = tid >> 6;
  unsigned gen = 0;

  // ---- prologue: q_temp / p_temp GEMMs ----
  for (int tt = blk; tt < 1840; tt += NBLK) {
    if (tt < 1600) {
      int d = tt / 800, rem = tt % 800, mt = rem >> 1, ntp = rem & 1;
      gemm_t<128, true, 1, (1 << 30), 0, 8>(sAh, sAl, warea,
          pin + (size_t)mt * BB * EE, EE, nullptr, 0,
          wpth + ((size_t)d * HH + ntp * 128) * EE,
          wptl + ((size_t)d * HH + ntp * 128) * EE, EE,
          pt + ((size_t)d * PL * BB + (size_t)mt * BB) * HH + ntp * 128, nullptr, HH,
          nullptr, nullptr, 0, nullptr, 0);
    } else {
      int u2 = tt - 1600;
      int d = u2 / 120, rem = u2 % 120, mt = rem >> 1, ntp = rem & 1;
      gemm_t<128, true, 1, (1 << 30), 0, 8>(sAh, sAl, warea,
          qin + (size_t)mt * BB * EE, EE, nullptr, 0,
          wqth + ((size_t)d * HH + ntp * 128) * EE,
          wqtl + ((size_t)d * HH + ntp * 128) * EE, EE,
          qt + ((size_t)d * QL * BB + (size_t)mt * BB) * HH + ntp * 128, nullptr, HH,
          nullptr, nullptr, 0, nullptr, 0);
    }
  }

  // ---- prologue: gh blocks load resident Whh hi/lo tile ----
  if (blk >= 160 && blk < 184) {
    const int g = blk - 160, d = g / 12, nt = g % 12;
    const unsigned short* sh = whhh + (size_t)(d * G3 + nt * 64) * HH;
    const unsigned short* sl = whhl + (size_t)(d * G3 + nt * 64) * HH;
    for (int i = tid; i < 16384; i += NTHR) {
      int ch = i >> 12, n = (i >> 6) & 63, k = i & 63;
      warea[(ch * 64 + n) * LDK + k]         = sh[(size_t)n * HH + ch * 64 + k];
      warea[18432 + (ch * 64 + n) * LDK + k] = sl[(size_t)n * HH + ch * 64 + k];
    }
  }

  // publish qt/pt (plain stores) once
  __builtin_amdgcn_fence(__ATOMIC_RELEASE, "agent");
  gbar(bar, ++gen);

  // per-(d,b) block-local state in LDS
  float* sm = fsm;            // 256
  float* sv = fsm + 256;      // 256
  float* slog = fsm + 512;    // 64
  float* swgt = fsm + 576;    // 64
  float* sstv = fsm + 640;    // 256 (state_temp; live C2 -> A only)
  float* spart = fsm + 896;   // 512
  float* hrow = fsm + 1408;   // 256
  if (tid < 256) sstv[tid] = 0.f;
  __syncthreads();

  const int d_ab = blk >> 7, b_ab = blk & 127;
  float hreg = 0.f;

  for (int s = 0; s < PL; ++s) {
    // ---------- phase A: attention (all blocks; one (d,b) each) ----------
    {
      const int d = d_ab, b = b_ab;
      const int t = d ? (PL - 1 - s) : s;
      if (tid < 256) {
        float ptv = __builtin_nontemporal_load(&pt[(((size_t)d * PL + t) * BB + b) * HH + tid]);
        sm[tid] = sstv[tid] + ptv;
        sv[tid] = vvec[d * HH + tid];
      }
      __syncthreads();
      for (int q = w; q < QL; q += 8) {
        float a = 0.f;
#pragma unroll
        for (int jj = 0; jj < 4; jj++) {
          int j = lane + jj * 64;
          a += ftanh(qt[(((size_t)d * QL + q) * BB + b) * HH + j] + sm[j]) * sv[j];
        }
        for (int off = 32; off; off >>= 1) a += __shfl_down(a, off, 64);
        if (lane == 0) slog[q] = a;
      }
      __syncthreads();
      if (tid < 64) {
        float x = -3.0e38f;
        if (lane < QL) {
          x = slog[lane];
          if (qmask[lane * BB + b]) x = -3.0e38f;
        }
        float mx = x;
        for (int off = 32; off; off >>= 1) mx = fmaxf(mx, __shfl_xor(mx, off, 64));
        float e = (lane < QL) ? __expf(x - mx) : 0.f;
        float sum2 = e;
        for (int off = 32; off; off >>= 1) sum2 += __shfl_xor(sum2, off, 64);
        if (lane < QL) swgt[lane] = e * __builtin_amdgcn_rcpf(sum2);
      }
      __syncthreads();
      {
        const int c = tid;  // 0..511
        float a0 = 0.f, a1 = 0.f, a2 = 0.f, a3 = 0.f;
        const float* qb = qin + (size_t)b * EE + c;
        for (int q = 0; q < QL; q += 4) {
          a0 += swgt[q]     * qb[(size_t)q * BB * EE];
          a1 += swgt[q + 1] * qb[(size_t)(q + 1) * BB * EE];
          a2 += swgt[q + 2] * qb[(size_t)(q + 2) * BB * EE];
          a3 += swgt[q + 3] * qb[(size_t)(q + 3) * BB * EE];
        }
        astu(&attp[((size_t)d * BB + b) * EE + c], packf((a0 + a1) + (a2 + a3)));
      }
    }
    gbar(bar, ++gen);

    // ---------- phase B: gate full-K (blocks 0-15) + gh (blocks 160-183) ----------
    if (blk < 16) {
      const int d = blk >> 3, nt = blk & 7;
      const int t = d ? (PL - 1 - s) : s;
      const float* pin_t = pin + (size_t)t * BB * EE;
      gemm_t<128, false, 2, EE, 2, 16>(sAh, sAl, warea,
          pin_t, EE,
          attp + (size_t)d * BB * EE, EE,
          gwh + ((size_t)d * DD + nt * 128) * DD, nullptr, DD,
          nullptr, xpack + (size_t)d * BB * DD + nt * 128, DD,
          (nt < 4) ? (pin_t + nt * 128) : nullptr,
          (nt >= 4) ? (attp + (size_t)d * BB * EE + (nt - 4) * 128) : nullptr, EE,
          gateb + (size_t)d * DD + nt * 128, 0);
    } else if (blk >= 160 && blk < 184) {
      const int g = blk - 160, d = g / 12, nt = g % 12;
      gemm_t<64, true, 0, 0, 1, 4>(sAh, sAl, warea,
          nullptr, 0,
          hpack + (size_t)d * BB * HH, HH,
          nullptr, nullptr, 0,
          ghp + (size_t)d * BB * G3 + nt * 64, nullptr, G3,
          nullptr, nullptr, 0, nullptr, 0);
    }
    gbar(bar, ++gen);

    // ---------- phase C1: gi full-K (blocks 64-75), A = xpack ----------
    if (blk >= 64 && blk < 76) {
      const int g = blk - 64, d = g / 6, nt = g % 6;
      gemm_t<128, true, 1, 0, 1, 16>(sAh, sAl, warea,
          nullptr, 0,
          xpack + (size_t)d * BB * DD, DD,
          wihh + ((size_t)d * G3 + nt * 128) * DD,
          wihl + ((size_t)d * G3 + nt * 128) * DD, DD,
          gif + (size_t)d * BB * G3 + nt * 128, nullptr, G3,
          nullptr, nullptr, 0, nullptr, 0);
    }
    gbar(bar, ++gen);

    // ---------- phase C2: GRU elementwise + output + state_temp GEMV ----------
    {
      const int d = d_ab, b = b_ab;
      const int j = tid & 255, half = tid >> 8;
      const int t = d ? (PL - 1 - s) : s;
      const size_t rb = (size_t)d * BB + b;
      float gi[3], gh[3];
#pragma unroll
      for (int c3 = 0; c3 < 3; c3++) {
        gi[c3] = ald(&gif[rb * G3 + c3 * HH + j]) + bih[(size_t)d * G3 + c3 * HH + j];
        gh[c3] = ald(&ghp[rb * G3 + c3 * HH + j]) + bhh[(size_t)d * G3 + c3 * HH + j];
      }
      float r = sigm(gi[0] + gh[0]);
      float z = sigm(gi[1] + gh[1]);
      float n = ftanh(gi[2] + r * gh[2]);
      float hn = (1.f - z) * n + z * hreg;
      hreg = hn;
      if (half == 0) {
        out[((size_t)t * BB + b) * 512 + d * HH + j] = hn;
        astu(&hpack[rb * HH + j], packf(hn));
        hrow[j] = hn;
      }
      __syncthreads();
      float part = 0.f;
      const float* wr = wst + ((size_t)d * HH + j) * HH + (half << 7);
      const float* hr = hrow + (half << 7);
#pragma unroll
      for (int k = 0; k < 128; k += 4) {
        float4 w4 = *(const float4*)&wr[k];
        float4 h4 = *(const float4*)&hr[k];
        part += w4.x * h4.x + w4.y * h4.y + w4.z * h4.z + w4.w * h4.w;
      }
      spart[tid] = part;
      __syncthreads();
      if (tid < 256) sstv[tid] = spart[tid] + spart[tid + 256];
      __syncthreads();
    }
    // C2 -> A: no grid barrier (A consumes only block-local state + static tensors)
  }
}

// ---------------- launch ----------------
extern "C" void kernel_launch(void* const* d_in, const int* in_sizes, int n_in,
                              void* d_out, int out_size, void* d_ws, size_t ws_size,
                              hipStream_t stream) {
  const float* qin = (const float*)d_in[0];
  const float* pin = (const float*)d_in[1];
  const unsigned char* qmask = (const unsigned char*)d_in[2];
  const float* Wq  = (const float*)d_in[3];
  const float* Wp  = (const float*)d_in[4];
  const float* Ws  = (const float*)d_in[5];
  const float* v   = (const float*)d_in[6];
  const float* gw  = (const float*)d_in[7];
  const float* gb  = (const float*)d_in[8];
  const float* wih = (const float*)d_in[9];
  const float* whh = (const float*)d_in[10];
  const float* bih = (const float*)d_in[11];
  const float* bhh = (const float*)d_in[12];
  float* out = (float*)d_out;

  char* base = (char*)d_ws;
  float* fws = (float*)base;
  unsigned* upck = (unsigned*)(base + F32_TOT * sizeof(float));
  unsigned short* hws = (unsigned short*)(base + F32_TOT * sizeof(float) + U_TOT * sizeof(unsigned));
  unsigned* bar = (unsigned*)(base + F32_TOT * sizeof(float) + U_TOT * sizeof(unsigned) +
                              H_TOT * sizeof(unsigned short));
  size_t need = F32_TOT * sizeof(float) + U_TOT * sizeof(unsigned) +
                H_TOT * sizeof(unsigned short) + 8192;
  if (ws_size < need) return;

  // zero h-state + barrier slots (re-runs on every graph replay)
  hipMemsetAsync(upck + UOFF_HPACK, 0, (size_t)2 * BB * HH * sizeof(unsigned), stream);
  hipMemsetAsync(bar, 0, 4096, stream);

  k_transpose_qp<<<128, 256, 0, stream>>>(Wq, Wp,
      hws + HOFF_WQTH, hws + HOFF_WQTL, hws + HOFF_WPTH, hws + HOFF_WPTL);
  k_split_w<<<1024, 256, 0, stream>>>(gw, wih, whh,
      hws + HOFF_GWH, hws + HOFF_GWL, hws + HOFF_WIHH, hws + HOFF_WIHL,
      hws + HOFF_WHHH, hws + HOFF_WHHL);
  k_wst<<<(int)((SZ_WST + 255) / 256), 256, 0, stream>>>(Ws, fws + OFF_WST);
  pe_main<<<NBLK, NTHR, 0, stream>>>(qin, pin, qmask, v, gb, bih, bhh, out,
                                     fws, upck, hws, bar);
}

// Round 6
// 31161.111 us; speedup vs baseline: 5.1929x; 5.1929x over previous
//
#include <hip/hip_runtime.h>

// ---------------- problem constants ----------------
#define PL 400
#define QL 60
#define BB 128
#define EE 512
#define HH 256
#define DD 1024
#define G3 768
#define NBLK 256
#define NTHR 512
#define LDK 72   // padded K stride (shorts) for LDS tiles

typedef __attribute__((ext_vector_type(8))) short bfrag;
typedef __attribute__((ext_vector_type(4))) float facc;

// ---------------- bf16 / math helpers ----------------
__device__ __forceinline__ unsigned short f2bf(float x) {
  unsigned u = __float_as_uint(x);
  return (unsigned short)((u + 0x7fffu + ((u >> 16) & 1u)) >> 16);
}
__device__ __forceinline__ float bf2f(unsigned short h) {
  return __uint_as_float(((unsigned)h) << 16);
}
__device__ __forceinline__ void split_bf(float x, unsigned short& hi, unsigned short& lo) {
  hi = f2bf(x);
  lo = f2bf(x - bf2f(hi));
}
__device__ __forceinline__ unsigned packf(float x) {
  unsigned short hi, lo;
  split_bf(x, hi, lo);
  return ((unsigned)hi << 16) | lo;
}
__device__ __forceinline__ float unpk(unsigned p) {
  return bf2f((unsigned short)(p >> 16)) + bf2f((unsigned short)(p & 0xffffu));
}
__device__ __forceinline__ float sigm(float x) {
  return __builtin_amdgcn_rcpf(1.f + __expf(-x));
}
__device__ __forceinline__ float ftanh(float x) {
  float xc = fminf(fmaxf(x, -10.f), 10.f);
  float t = __expf(2.f * xc);
  return (t - 1.f) * __builtin_amdgcn_rcpf(t + 1.f);
}

// ---------------- agent-scope relaxed atomics (MALL-coherent) ----------------
__device__ __forceinline__ float ald(const float* p) {
  return __hip_atomic_load((float*)p, __ATOMIC_RELAXED, __HIP_MEMORY_SCOPE_AGENT);
}
__device__ __forceinline__ void ast(float* p, float v) {
  __hip_atomic_store(p, v, __ATOMIC_RELAXED, __HIP_MEMORY_SCOPE_AGENT);
}
__device__ __forceinline__ unsigned aldu(const unsigned* p) {
  return __hip_atomic_load((unsigned*)p, __ATOMIC_RELAXED, __HIP_MEMORY_SCOPE_AGENT);
}
__device__ __forceinline__ void astu(unsigned* p, unsigned v) {
  __hip_atomic_store(p, v, __ATOMIC_RELAXED, __HIP_MEMORY_SCOPE_AGENT);
}

// ---------------- ws layout ----------------
// fp32 region
constexpr size_t SZ_QT  = (size_t)2 * QL * BB * HH;
constexpr size_t SZ_PT  = (size_t)2 * PL * BB * HH;
constexpr size_t SZ_GIP = (size_t)2 * 4 * BB * G3;  // gi partials (k-split 4), [d][ks][b][768]
constexpr size_t SZ_GHP = (size_t)2 * BB * G3;      // gh final
constexpr size_t SZ_WST = (size_t)2 * HH * HH;      // Ws transposed
constexpr size_t OFF_QT  = 0;
constexpr size_t OFF_PT  = OFF_QT + SZ_QT;
constexpr size_t OFF_GIP = OFF_PT + SZ_PT;
constexpr size_t OFF_GHP = OFF_GIP + SZ_GIP;
constexpr size_t OFF_WST = OFF_GHP + SZ_GHP;
constexpr size_t F32_TOT = OFF_WST + SZ_WST;
// uint region (packed hi/lo bf16)
constexpr size_t UOFF_ATTP  = 0;                                // [d][b][512]
constexpr size_t UOFF_XPACK = UOFF_ATTP + (size_t)2 * BB * EE;  // [d][b][1024]
constexpr size_t UOFF_HPACK = UOFF_XPACK + (size_t)2 * BB * DD; // [d][b][256]
constexpr size_t U_TOT      = UOFF_HPACK + (size_t)2 * BB * HH;
// bf16 (ushort) weight region
constexpr size_t HSZ_WQT = (size_t)2 * HH * EE;
constexpr size_t HSZ_GW  = (size_t)2 * DD * DD;
constexpr size_t HSZ_WIH = (size_t)2 * G3 * DD;
constexpr size_t HSZ_WHH = (size_t)2 * G3 * HH;
constexpr size_t HOFF_WQTH = 0;
constexpr size_t HOFF_WQTL = HOFF_WQTH + HSZ_WQT;
constexpr size_t HOFF_WPTH = HOFF_WQTL + HSZ_WQT;
constexpr size_t HOFF_WPTL = HOFF_WPTH + HSZ_WQT;
constexpr size_t HOFF_GWH  = HOFF_WPTL + HSZ_WQT;
constexpr size_t HOFF_GWL  = HOFF_GWH + HSZ_GW;
constexpr size_t HOFF_WIHH = HOFF_GWL + HSZ_GW;
constexpr size_t HOFF_WIHL = HOFF_WIHH + HSZ_WIH;
constexpr size_t HOFF_WHHH = HOFF_WIHL + HSZ_WIH;
constexpr size_t HOFF_WHHL = HOFF_WHHH + HSZ_WHH;
constexpr size_t H_TOT     = HOFF_WHHL + HSZ_WHH;

// ---------------- grid barrier: flat all-poll, fence-free ----------------
__device__ __forceinline__ void gbar(unsigned* slots, unsigned gen) {
  asm volatile("" ::: "memory");
  __syncthreads();  // drains vmcnt for all waves of this block (release point)
  if (threadIdx.x == 0)
    __hip_atomic_store(&slots[blockIdx.x], gen, __ATOMIC_RELAXED, __HIP_MEMORY_SCOPE_AGENT);
  if (threadIdx.x < NBLK) {
    unsigned sp = 0;
    while (__hip_atomic_load(&slots[threadIdx.x], __ATOMIC_RELAXED, __HIP_MEMORY_SCOPE_AGENT) < gen) {
      __builtin_amdgcn_s_sleep(1);
      if (++sp > (1u << 26)) break;  // hang bailout
    }
  }
  __syncthreads();
  asm volatile("" ::: "memory");
}

// ---------------- unified MFMA GEMM tile ----------------
// M=128 (batch rows). NT = 128/64/32 output cols. K = NCH*64 from kbase.
// A source per chunk: kk < SPLITK -> fp32 a32[r*a32s+kk] (split hi/lo);
//                     else packed apk[r*apks + kk - SPLITK] (unpack).
// One-chunk-deep register prefetch of the 4B A-words.
// BG: 0 = B resident in warea (chunk-major), 1 = stream hi/lo from global (prologue).
// EPI: 0 = plain fp32 store; 1 = atomic fp32 store;
//      2 = gate: x = u * sigm(acc + gbv[col]), packed store to dstu.
template <int NT, bool BSPLIT, int BG, int SPLITK, int EPI, int NCH>
__device__ void gemm_t(unsigned short* sAh, unsigned short* sAl, unsigned short* warea,
                       const float* a32, int a32s,
                       const unsigned* apk, int apks,
                       const unsigned short* bh_g, const unsigned short* bl_g, int bstride,
                       float* dstf, unsigned* dstu, int dstride,
                       const float* uf_src, const unsigned* up_src, int ustride,
                       const float* gbv, int kbase) {
  const int tid = threadIdx.x;
  const int lane = tid & 63;
  const int w = tid >> 6;
  constexpr int FM = (NT == 128) ? 4 : 2;
  constexpr int FN = (NT == 32) ? 1 : 2;
  const int wm = (NT == 128) ? ((w >> 2) << 6) : ((w >> 1) << 5);
  const int wn = (NT == 128) ? ((w & 3) << 5) : ((NT == 64) ? ((w & 1) << 5) : ((w & 1) << 4));
  const int lr = lane & 15;
  const int lk = (lane >> 4) << 3;

  unsigned short* wh = warea;
  unsigned short* wl = (BG == 0) ? (warea + NCH * NT * LDK) : (warea + NT * LDK);

  const facc fz = {0.f, 0.f, 0.f, 0.f};
  facc acc[FM][FN];
#pragma unroll
  for (int i = 0; i < FM; i++)
#pragma unroll
    for (int j = 0; j < FN; j++) acc[i][j] = fz;

  unsigned pva[16], pvb[16];
  {
#pragma unroll
    for (int ii = 0; ii < 16; ii++) {
      int r = ii * 8 + w;
      if (kbase < SPLITK)
        pva[ii] = __float_as_uint(a32[(size_t)r * a32s + kbase + lane]);
      else
        pva[ii] = aldu(&apk[(size_t)r * apks + kbase - SPLITK + lane]);
    }
  }

#pragma unroll
  for (int ch = 0; ch < NCH; ++ch) {
    const int kk0 = kbase + (ch << 6);
    unsigned* cur = (ch & 1) ? pvb : pva;
    unsigned* nxt = (ch & 1) ? pva : pvb;
    // ---- B stream (prologue only) ----
    if constexpr (BG == 1) {
#pragma unroll
      for (int i2 = 0; i2 < NT * 64 / NTHR; i2++) {
        int i = i2 * NTHR + tid;
        int n = i >> 6, k = i & 63;
        wh[n * LDK + k] = bh_g[(size_t)n * bstride + kk0 + k];
        wl[n * LDK + k] = bl_g[(size_t)n * bstride + kk0 + k];
      }
    }
    // ---- A prefetch next chunk (stays in flight across barrier) ----
    if (ch + 1 < NCH) {
      const int kk1 = kk0 + 64;
#pragma unroll
      for (int ii = 0; ii < 16; ii++) {
        int r = ii * 8 + w;
        if (kk1 < SPLITK)
          nxt[ii] = __float_as_uint(a32[(size_t)r * a32s + kk1 + lane]);
        else
          nxt[ii] = aldu(&apk[(size_t)r * apks + kk1 - SPLITK + lane]);
      }
    }
    // ---- A convert + LDS store (regs from previous prefetch) ----
    const bool f32c = (kk0 < SPLITK);
#pragma unroll
    for (int ii = 0; ii < 16; ii++) {
      int r = ii * 8 + w;
      unsigned p = cur[ii];
      unsigned short uh, ul;
      if (f32c) split_bf(__uint_as_float(p), uh, ul);
      else { uh = (unsigned short)(p >> 16); ul = (unsigned short)(p & 0xffffu); }
      sAh[r * LDK + lane] = uh;
      sAl[r * LDK + lane] = ul;
    }
    if constexpr (BG == 1) {
      __syncthreads();  // streamed B must be complete (vmcnt drain ok in prologue)
    } else {
      asm volatile("s_waitcnt lgkmcnt(0)" ::: "memory");
      __builtin_amdgcn_s_barrier();
      __builtin_amdgcn_sched_barrier(0);
    }

    const int wch = (BG == 0) ? ch : 0;
#pragma unroll
    for (int k32 = 0; k32 < 64; k32 += 32) {
      bfrag ah[FM], al_[FM], bhf[FN], blf[FN];
#pragma unroll
      for (int f = 0; f < FM; f++) {
        const int ao = (wm + (f << 4) + lr) * LDK + k32 + lk;
        ah[f]  = *(const bfrag*)&sAh[ao];
        al_[f] = *(const bfrag*)&sAl[ao];
      }
#pragma unroll
      for (int f = 0; f < FN; f++) {
        const int bo = (wch * NT + wn + (f << 4) + lr) * LDK + k32 + lk;
        bhf[f] = *(const bfrag*)&wh[bo];
        if constexpr (BSPLIT) blf[f] = *(const bfrag*)&wl[bo];
      }
#pragma unroll
      for (int i = 0; i < FM; i++)
#pragma unroll
        for (int j = 0; j < FN; j++) {
          acc[i][j] = __builtin_amdgcn_mfma_f32_16x16x32_bf16(al_[i], bhf[j], acc[i][j], 0, 0, 0);
          if constexpr (BSPLIT)
            acc[i][j] = __builtin_amdgcn_mfma_f32_16x16x32_bf16(ah[i], blf[j], acc[i][j], 0, 0, 0);
          acc[i][j] = __builtin_amdgcn_mfma_f32_16x16x32_bf16(ah[i], bhf[j], acc[i][j], 0, 0, 0);
        }
    }
    __builtin_amdgcn_sched_barrier(0);
    __builtin_amdgcn_s_barrier();
    __builtin_amdgcn_sched_barrier(0);
  }
  // ---- epilogue ----
  const int orow = (lane >> 4) << 2;
  const int ocol = lane & 15;
#pragma unroll
  for (int i = 0; i < FM; i++)
#pragma unroll
    for (int j = 0; j < FN; j++)
#pragma unroll
      for (int q = 0; q < 4; q++) {
        const int row = wm + (i << 4) + orow + q;
        const int col = wn + (j << 4) + ocol;
        float val = acc[i][j][q];
        if constexpr (EPI == 0) {
          dstf[(size_t)row * dstride + col] = val;
        } else if constexpr (EPI == 1) {
          ast(&dstf[(size_t)row * dstride + col], val);
        } else {
          float uv = uf_src ? uf_src[(size_t)row * ustride + col]
                            : unpk(aldu(&up_src[(size_t)row * ustride + col]));
          float x = uv * sigm(val + gbv[col]);
          astu(&dstu[(size_t)row * dstride + col], packf(x));
        }
      }
}

// ---------------- setup kernels ----------------
__global__ void __launch_bounds__(256) k_transpose_qp(
    const float* __restrict__ Wq, const float* __restrict__ Wp,
    unsigned short* __restrict__ wqth, unsigned short* __restrict__ wqtl,
    unsigned short* __restrict__ wpth, unsigned short* __restrict__ wptl) {
  __shared__ float tile[64 * 65];
  const int blk = blockIdx.x;
  const int mat = blk >> 6;
  const int rem = blk & 63;
  const int d = rem >> 5;
  const int rem2 = rem & 31;
  const int kt = rem2 >> 2;
  const int nt = rem2 & 3;
  const float* src = mat ? Wp : Wq;
  unsigned short* dh = mat ? wpth : wqth;
  unsigned short* dl = mat ? wptl : wqtl;
  const int tid = threadIdx.x;
  for (int i = tid; i < 4096; i += 256) {
    int kr = i >> 6, nc = i & 63;
    tile[kr * 65 + nc] = src[((size_t)d * EE + kt * 64 + kr) * HH + nt * 64 + nc];
  }
  __syncthreads();
  for (int i = tid; i < 4096; i += 256) {
    int n = i >> 6, k = i & 63;
    unsigned short hi, lo;
    split_bf(tile[k * 65 + n], hi, lo);
    size_t o = ((size_t)d * HH + nt * 64 + n) * EE + kt * 64 + k;
    dh[o] = hi; dl[o] = lo;
  }
}

__global__ void __launch_bounds__(256) k_split_w(
    const float* __restrict__ gw, const float* __restrict__ wih, const float* __restrict__ whh,
    unsigned short* __restrict__ gwh, unsigned short* __restrict__ gwl,
    unsigned short* __restrict__ wihh, unsigned short* __restrict__ wihl,
    unsigned short* __restrict__ whhh, unsigned short* __restrict__ whhl) {
  const size_t N1 = HSZ_GW, N2 = HSZ_WIH, N3 = HSZ_WHH;
  for (size_t i = (size_t)blockIdx.x * 256 + threadIdx.x; i < N1 + N2 + N3;
       i += (size_t)gridDim.x * 256) {
    float x; unsigned short *ph, *pl; size_t o;
    if (i < N1)           { o = i;           x = gw[o];  ph = gwh;  pl = gwl; }
    else if (i < N1 + N2) { o = i - N1;      x = wih[o]; ph = wihh; pl = wihl; }
    else                  { o = i - N1 - N2; x = whh[o]; ph = whhh; pl = whhl; }
    unsigned short hi, lo;
    split_bf(x, hi, lo);
    ph[o] = hi; pl[o] = lo;
  }
}

__global__ void __launch_bounds__(256) k_wst(const float* __restrict__ Ws,
                                             float* __restrict__ wst) {
  size_t i = (size_t)blockIdx.x * 256 + threadIdx.x;
  if (i >= SZ_WST) return;
  int d = (int)(i >> 16);
  int j = (int)((i >> 8) & 255);
  int k = (int)(i & 255);
  wst[i] = Ws[((size_t)d * HH + k) * HH + j];
}

// ---------------- the persistent kernel ----------------
__global__ void __launch_bounds__(NTHR, 1) pe_main(
    const float* __restrict__ qin, const float* __restrict__ pin,
    const unsigned char* __restrict__ qmask,
    const float* __restrict__ vvec, const float* __restrict__ gateb,
    const float* __restrict__ bih, const float* __restrict__ bhh,
    float* __restrict__ out,
    float* __restrict__ fws, unsigned* __restrict__ upck,
    unsigned short* __restrict__ hws, unsigned* __restrict__ bar) {
  __shared__ __align__(16) unsigned short smem[55296];  // 110.6 KB
  unsigned short* sAh = smem;            // 9216 shorts
  unsigned short* sAl = smem + 9216;     // 9216 shorts
  unsigned short* warea = smem + 18432;  // 36864 shorts (resident weights / prologue B)
  float* fsm = (float*)smem;             // phase A / C2 scratch (aliases sAh/sAl)

  float* qt   = fws + OFF_QT;
  float* pt   = fws + OFF_PT;
  float* gip  = fws + OFF_GIP;
  float* ghp  = fws + OFF_GHP;
  float* wst  = fws + OFF_WST;
  unsigned* attp  = upck + UOFF_ATTP;
  unsigned* xpack = upck + UOFF_XPACK;
  unsigned* hpack = upck + UOFF_HPACK;
  unsigned short* wqth = hws + HOFF_WQTH;
  unsigned short* wqtl = hws + HOFF_WQTL;
  unsigned short* wpth = hws + HOFF_WPTH;
  unsigned short* wptl = hws + HOFF_WPTL;
  unsigned short* gwh  = hws + HOFF_GWH;
  unsigned short* wihh = hws + HOFF_WIHH;
  unsigned short* wihl = hws + HOFF_WIHL;
  unsigned short* whhh = hws + HOFF_WHHH;
  unsigned short* whhl = hws + HOFF_WHHL;

  const int blk = blockIdx.x;
  const int tid = threadIdx.x;
  const int lane = tid & 63;
  const int w = tid >> 6;
  unsigned gen = 0;

  // ---- prologue: q_temp / p_temp GEMMs (warea used for B streaming) ----
  for (int tt = blk; tt < 1840; tt += NBLK) {
    if (tt < 1600) {
      int d = tt / 800, rem = tt % 800, mt = rem >> 1, ntp = rem & 1;
      gemm_t<128, true, 1, (1 << 30), 0, 8>(sAh, sAl, warea,
          pin + (size_t)mt * BB * EE, EE, nullptr, 0,
          wpth + ((size_t)d * HH + ntp * 128) * EE,
          wptl + ((size_t)d * HH + ntp * 128) * EE, EE,
          pt + ((size_t)d * PL * BB + (size_t)mt * BB) * HH + ntp * 128, nullptr, HH,
          nullptr, nullptr, 0, nullptr, 0);
    } else {
      int u2 = tt - 1600;
      int d = u2 / 120, rem = u2 % 120, mt = rem >> 1, ntp = rem & 1;
      gemm_t<128, true, 1, (1 << 30), 0, 8>(sAh, sAl, warea,
          qin + (size_t)mt * BB * EE, EE, nullptr, 0,
          wqth + ((size_t)d * HH + ntp * 128) * EE,
          wqtl + ((size_t)d * HH + ntp * 128) * EE, EE,
          qt + ((size_t)d * QL * BB + (size_t)mt * BB) * HH + ntp * 128, nullptr, HH,
          nullptr, nullptr, 0, nullptr, 0);
    }
  }

  // ---- prologue: load this block's resident weight tile into LDS ----
  if (blk < 64) {               // gate: 32 cols, full K=1024, single bf16 (64 KB)
    const int d = blk >> 5, ct = blk & 31;
    const unsigned short* src = gwh + (size_t)(d * DD + ct * 32) * DD;
    for (int i = tid; i < 32768; i += NTHR) {
      int ch = i >> 11, n = (i >> 6) & 31, k = i & 63;
      warea[(ch * 32 + n) * LDK + k] = src[(size_t)n * DD + ch * 64 + k];
    }
  } else if (blk < 160) {       // gi: Wih hi/lo, NT=64, K-range 256
    const int g = blk - 64, d = g / 48, r = g % 48, nt = r >> 2, ks = r & 3;
    const unsigned short* sh = wihh + (size_t)(d * G3 + nt * 64) * DD + ks * 256;
    const unsigned short* sl = wihl + (size_t)(d * G3 + nt * 64) * DD + ks * 256;
    for (int i = tid; i < 16384; i += NTHR) {
      int ch = i >> 12, n = (i >> 6) & 63, k = i & 63;
      warea[(ch * 64 + n) * LDK + k]         = sh[(size_t)n * DD + ch * 64 + k];
      warea[18432 + (ch * 64 + n) * LDK + k] = sl[(size_t)n * DD + ch * 64 + k];
    }
  } else if (blk < 184) {       // gh: Whh hi/lo, NT=64, K=256
    const int g = blk - 160, d = g / 12, nt = g % 12;
    const unsigned short* sh = whhh + (size_t)(d * G3 + nt * 64) * HH;
    const unsigned short* sl = whhl + (size_t)(d * G3 + nt * 64) * HH;
    for (int i = tid; i < 16384; i += NTHR) {
      int ch = i >> 12, n = (i >> 6) & 63, k = i & 63;
      warea[(ch * 64 + n) * LDK + k]         = sh[(size_t)n * HH + ch * 64 + k];
      warea[18432 + (ch * 64 + n) * LDK + k] = sl[(size_t)n * HH + ch * 64 + k];
    }
  }

  // publish qt/pt (plain stores) once
  __builtin_amdgcn_fence(__ATOMIC_RELEASE, "agent");
  gbar(bar, ++gen);

  // per-(d,b) block-local state in LDS
  float* sm = fsm;            // 256
  float* sv = fsm + 256;      // 256
  float* slog = fsm + 512;    // 64
  float* swgt = fsm + 576;    // 64
  float* sstv = fsm + 640;    // 256 (state_temp; live C2 -> A only)
  float* spart = fsm + 896;   // 512
  float* hrow = fsm + 1408;   // 256
  if (tid < 256) sstv[tid] = 0.f;
  __syncthreads();

  const int d_ab = blk >> 7, b_ab = blk & 127;
  float hreg = 0.f;

  for (int s = 0; s < PL; ++s) {
    // ---------- phase A: attention (all blocks; one (d,b) each) ----------
    {
      const int d = d_ab, b = b_ab;
      const int t = d ? (PL - 1 - s) : s;
      if (tid < 256) {
        float ptv = __builtin_nontemporal_load(&pt[(((size_t)d * PL + t) * BB + b) * HH + tid]);
        sm[tid] = sstv[tid] + ptv;
        sv[tid] = vvec[d * HH + tid];
      }
      __syncthreads();
      for (int q = w; q < QL; q += 8) {
        float a = 0.f;
#pragma unroll
        for (int jj = 0; jj < 4; jj++) {
          int j = lane + jj * 64;
          a += ftanh(qt[(((size_t)d * QL + q) * BB + b) * HH + j] + sm[j]) * sv[j];
        }
        for (int off = 32; off; off >>= 1) a += __shfl_down(a, off, 64);
        if (lane == 0) slog[q] = a;
      }
      __syncthreads();
      if (tid < 64) {
        float x = -3.0e38f;
        if (lane < QL) {
          x = slog[lane];
          if (qmask[lane * BB + b]) x = -3.0e38f;
        }
        float mx = x;
        for (int off = 32; off; off >>= 1) mx = fmaxf(mx, __shfl_xor(mx, off, 64));
        float e = (lane < QL) ? __expf(x - mx) : 0.f;
        float sum2 = e;
        for (int off = 32; off; off >>= 1) sum2 += __shfl_xor(sum2, off, 64);
        if (lane < QL) swgt[lane] = e * __builtin_amdgcn_rcpf(sum2);
      }
      __syncthreads();
      {
        const int c = tid;  // 0..511
        float a0 = 0.f, a1 = 0.f, a2 = 0.f, a3 = 0.f;
        const float* qb = qin + (size_t)b * EE + c;
        for (int q = 0; q < QL; q += 4) {
          a0 += swgt[q]     * qb[(size_t)q * BB * EE];
          a1 += swgt[q + 1] * qb[(size_t)(q + 1) * BB * EE];
          a2 += swgt[q + 2] * qb[(size_t)(q + 2) * BB * EE];
          a3 += swgt[q + 3] * qb[(size_t)(q + 3) * BB * EE];
        }
        astu(&attp[((size_t)d * BB + b) * EE + c], packf((a0 + a1) + (a2 + a3)));
      }
    }
    gbar(bar, ++gen);

    // ---------- phase B: gate full-K N=32 (blocks 0-63) + gh (160-183) ----------
    if (blk < 64) {
      const int d = blk >> 5, ct = blk & 31;
      const int t = d ? (PL - 1 - s) : s;
      const float* pin_t = pin + (size_t)t * BB * EE;
      const int coloff = ct * 32;
      gemm_t<32, false, 0, EE, 2, 16>(sAh, sAl, warea,
          pin_t, EE,
          attp + (size_t)d * BB * EE, EE,
          nullptr, nullptr, 0,
          nullptr, xpack + (size_t)d * BB * DD + coloff, DD,
          (ct < 16) ? (pin_t + coloff) : nullptr,
          (ct < 16) ? nullptr : (attp + (size_t)d * BB * EE + (coloff - EE)), EE,
          gateb + (size_t)d * DD + coloff, 0);
    } else if (blk >= 160 && blk < 184) {
      const int g = blk - 160, d = g / 12, nt = g % 12;
      gemm_t<64, true, 0, 0, 1, 4>(sAh, sAl, warea,
          nullptr, 0,
          hpack + (size_t)d * BB * HH, HH,
          nullptr, nullptr, 0,
          ghp + (size_t)d * BB * G3 + nt * 64, nullptr, G3,
          nullptr, nullptr, 0, nullptr, 0);
    }
    gbar(bar, ++gen);

    // ---------- phase C1: gi partials (blocks 64-159), A = xpack ----------
    if (blk >= 64 && blk < 160) {
      const int g = blk - 64, d = g / 48, r = g % 48, nt = r >> 2, ks = r & 3;
      gemm_t<64, true, 0, 0, 1, 4>(sAh, sAl, warea,
          nullptr, 0,
          xpack + (size_t)d * BB * DD, DD,
          nullptr, nullptr, 0,
          gip + ((size_t)(d * 4 + ks) * BB) * G3 + nt * 64, nullptr, G3,
          nullptr, nullptr, 0, nullptr, ks * 256);
    }
    gbar(bar, ++gen);

    // ---------- phase C2: GRU elementwise + output + state_temp GEMV ----------
    {
      const int d = d_ab, b = b_ab;
      const int j = tid & 255, half = tid >> 8;
      const int t = d ? (PL - 1 - s) : s;
      const size_t rb = (size_t)d * BB + b;
      float gi[3], gh[3];
#pragma unroll
      for (int c3 = 0; c3 < 3; c3++) {
        float acc2 = bih[(size_t)d * G3 + c3 * HH + j];
#pragma unroll
        for (int ks = 0; ks < 4; ks++)
          acc2 += ald(&gip[((size_t)(d * 4 + ks) * BB + b) * G3 + c3 * HH + j]);
        gi[c3] = acc2;
        gh[c3] = ald(&ghp[rb * G3 + c3 * HH + j]) + bhh[(size_t)d * G3 + c3 * HH + j];
      }
      float r = sigm(gi[0] + gh[0]);
      float z = sigm(gi[1] + gh[1]);
      float n = ftanh(gi[2] + r * gh[2]);
      float hn = (1.f - z) * n + z * hreg;
      hreg = hn;
      if (half == 0) {
        out[((size_t)t * BB + b) * 512 + d * HH + j] = hn;
        astu(&hpack[rb * HH + j], packf(hn));
        hrow[j] = hn;
      }
      __syncthreads();
      float part = 0.f;
      const float* wr = wst + ((size_t)d * HH + j) * HH + (half << 7);
      const float* hr = hrow + (half << 7);
#pragma unroll
      for (int k = 0; k < 128; k += 4) {
        float4 w4 = *(const float4*)&wr[k];
        float4 h4 = *(const float4*)&hr[k];
        part += w4.x * h4.x + w4.y * h4.y + w4.z * h4.z + w4.w * h4.w;
      }
      spart[tid] = part;
      __syncthreads();
      if (tid < 256) sstv[tid] = spart[tid] + spart[tid + 256];
      __syncthreads();
    }
    // C2 -> A: no grid barrier (A consumes only block-local state + static tensors)
  }
}

// ---------------- launch ----------------
extern "C" void kernel_launch(void* const* d_in, const int* in_sizes, int n_in,
                              void* d_out, int out_size, void* d_ws, size_t ws_size,
                              hipStream_t stream) {
  const float* qin = (const float*)d_in[0];
  const float* pin = (const float*)d_in[1];
  const unsigned char* qmask = (const unsigned char*)d_in[2];
  const float* Wq  = (const float*)d_in[3];
  const float* Wp  = (const float*)d_in[4];
  const float* Ws  = (const float*)d_in[5];
  const float* v   = (const float*)d_in[6];
  const float* gw  = (const float*)d_in[7];
  const float* gb  = (const float*)d_in[8];
  const float* wih = (const float*)d_in[9];
  const float* whh = (const float*)d_in[10];
  const float* bih = (const float*)d_in[11];
  const float* bhh = (const float*)d_in[12];
  float* out = (float*)d_out;

  char* base = (char*)d_ws;
  float* fws = (float*)base;
  unsigned* upck = (unsigned*)(base + F32_TOT * sizeof(float));
  unsigned short* hws = (unsigned short*)(base + F32_TOT * sizeof(float) + U_TOT * sizeof(unsigned));
  unsigned* bar = (unsigned*)(base + F32_TOT * sizeof(float) + U_TOT * sizeof(unsigned) +
                              H_TOT * sizeof(unsigned short));
  size_t need = F32_TOT * sizeof(float) + U_TOT * sizeof(unsigned) +
                H_TOT * sizeof(unsigned short) + 8192;
  if (ws_size < need) return;

  // zero h-state + barrier slots (re-runs on every graph replay)
  hipMemsetAsync(upck + UOFF_HPACK, 0, (size_t)2 * BB * HH * sizeof(unsigned), stream);
  hipMemsetAsync(bar, 0, 4096, stream);

  k_transpose_qp<<<128, 256, 0, stream>>>(Wq, Wp,
      hws + HOFF_WQTH, hws + HOFF_WQTL, hws + HOFF_WPTH, hws + HOFF_WPTL);
  k_split_w<<<1024, 256, 0, stream>>>(gw, wih, whh,
      hws + HOFF_GWH, hws + HOFF_GWL, hws + HOFF_WIHH, hws + HOFF_WIHL,
      hws + HOFF_WHHH, hws + HOFF_WHHL);
  k_wst<<<(int)((SZ_WST + 255) / 256), 256, 0, stream>>>(Ws, fws + OFF_WST);
  pe_main<<<NBLK, NTHR, 0, stream>>>(qin, pin, qmask, v, gb, bih, bhh, out,
                                     fws, upck, hws, bar);
}

// Round 7
// 25547.981 us; speedup vs baseline: 6.3338x; 1.2197x over previous
//
#include <hip/hip_runtime.h>

// ---------------- problem constants ----------------
#define PL 400
#define QL 60
#define BB 128
#define EE 512
#define HH 256
#define DD 1024
#define G3 768
#define NBLK 256
#define NTHR 512
#define LDK 72   // padded K stride (shorts) for LDS tiles

typedef __attribute__((ext_vector_type(8))) short bfrag;
typedef __attribute__((ext_vector_type(4))) float facc;

// ---------------- bf16 / math helpers ----------------
__device__ __forceinline__ unsigned short f2bf(float x) {
  unsigned u = __float_as_uint(x);
  return (unsigned short)((u + 0x7fffu + ((u >> 16) & 1u)) >> 16);
}
__device__ __forceinline__ float bf2f(unsigned short h) {
  return __uint_as_float(((unsigned)h) << 16);
}
__device__ __forceinline__ void split_bf(float x, unsigned short& hi, unsigned short& lo) {
  hi = f2bf(x);
  lo = f2bf(x - bf2f(hi));
}
__device__ __forceinline__ unsigned packf(float x) {
  unsigned short hi, lo;
  split_bf(x, hi, lo);
  return ((unsigned)hi << 16) | lo;
}
__device__ __forceinline__ float unpk(unsigned p) {
  return bf2f((unsigned short)(p >> 16)) + bf2f((unsigned short)(p & 0xffffu));
}
__device__ __forceinline__ float sigm(float x) {
  return __builtin_amdgcn_rcpf(1.f + __expf(-x));
}
__device__ __forceinline__ float ftanh(float x) {
  float xc = fminf(fmaxf(x, -10.f), 10.f);
  float t = __expf(2.f * xc);
  return (t - 1.f) * __builtin_amdgcn_rcpf(t + 1.f);
}

// ---------------- agent-scope relaxed atomics (MALL-coherent) ----------------
__device__ __forceinline__ float ald(const float* p) {
  return __hip_atomic_load((float*)p, __ATOMIC_RELAXED, __HIP_MEMORY_SCOPE_AGENT);
}
__device__ __forceinline__ void ast(float* p, float v) {
  __hip_atomic_store(p, v, __ATOMIC_RELAXED, __HIP_MEMORY_SCOPE_AGENT);
}
__device__ __forceinline__ unsigned aldu(const unsigned* p) {
  return __hip_atomic_load((unsigned*)p, __ATOMIC_RELAXED, __HIP_MEMORY_SCOPE_AGENT);
}
__device__ __forceinline__ void astu(unsigned* p, unsigned v) {
  __hip_atomic_store(p, v, __ATOMIC_RELAXED, __HIP_MEMORY_SCOPE_AGENT);
}
__device__ __forceinline__ void pollge(unsigned* f, unsigned tgt) {
  unsigned sp = 0;
  while (aldu(f) < tgt) {
    __builtin_amdgcn_s_sleep(1);
    if (++sp > (1u << 26)) break;  // hang bailout
  }
}

// ---------------- ws layout ----------------
// fp32 region
constexpr size_t SZ_QT  = (size_t)2 * QL * BB * HH;
constexpr size_t SZ_PT  = (size_t)2 * PL * BB * HH;
constexpr size_t SZ_GIP = (size_t)2 * 4 * BB * G3;  // gi partials (k-split 4)
constexpr size_t SZ_GHP = (size_t)2 * BB * G3;      // gh final
constexpr size_t SZ_WST = (size_t)2 * HH * HH;      // Ws transposed
constexpr size_t OFF_QT  = 0;
constexpr size_t OFF_PT  = OFF_QT + SZ_QT;
constexpr size_t OFF_GIP = OFF_PT + SZ_PT;
constexpr size_t OFF_GHP = OFF_GIP + SZ_GIP;
constexpr size_t OFF_WST = OFF_GHP + SZ_GHP;
constexpr size_t F32_TOT = OFF_WST + SZ_WST;
// uint region (packed hi/lo bf16); attp & xpack are parity double-buffered
constexpr size_t UOFF_ATTP  = 0;                                    // [2][d][b][512]
constexpr size_t UOFF_XPACK = UOFF_ATTP + (size_t)2 * 2 * BB * EE;  // [2][d][b][1024]
constexpr size_t UOFF_HPACK = UOFF_XPACK + (size_t)2 * 2 * BB * DD; // [d][b][256]
constexpr size_t U_TOT      = UOFF_HPACK + (size_t)2 * BB * HH;
// bf16 (ushort) weight region
constexpr size_t HSZ_WQT = (size_t)2 * HH * EE;
constexpr size_t HSZ_GW  = (size_t)2 * DD * DD;
constexpr size_t HSZ_WIH = (size_t)2 * G3 * DD;
constexpr size_t HSZ_WHH = (size_t)2 * G3 * HH;
constexpr size_t HOFF_WQTH = 0;
constexpr size_t HOFF_WQTL = HOFF_WQTH + HSZ_WQT;
constexpr size_t HOFF_WPTH = HOFF_WQTL + HSZ_WQT;
constexpr size_t HOFF_WPTL = HOFF_WPTH + HSZ_WQT;
constexpr size_t HOFF_GWH  = HOFF_WPTL + HSZ_WQT;
constexpr size_t HOFF_GWL  = HOFF_GWH + HSZ_GW;
constexpr size_t HOFF_WIHH = HOFF_GWL + HSZ_GW;
constexpr size_t HOFF_WIHL = HOFF_WIHH + HSZ_WIH;
constexpr size_t HOFF_WHHH = HOFF_WIHL + HSZ_WIH;
constexpr size_t HOFF_WHHL = HOFF_WHHH + HSZ_WHH;
constexpr size_t H_TOT     = HOFF_WHHL + HSZ_WHH;

// flag indices (uints, after the 256 prologue-barrier slots)
#define FA 0     // [d*128+b]   att done, value s+1
#define FG 256   // [d*32+ct]   gate done
#define FI 320   // [d*48+r]    gi done
#define FH 416   // [d*12+nt]   gh done
#define FC 440   // [d*128+b]   C2/hpack done

// ---------------- prologue grid barrier (flat all-poll) ----------------
__device__ __forceinline__ void gbar(unsigned* slots, unsigned gen) {
  asm volatile("" ::: "memory");
  __syncthreads();
  if (threadIdx.x == 0)
    __hip_atomic_store(&slots[blockIdx.x], gen, __ATOMIC_RELAXED, __HIP_MEMORY_SCOPE_AGENT);
  if (threadIdx.x < NBLK) pollge(&slots[threadIdx.x], gen);
  __syncthreads();
  asm volatile("" ::: "memory");
}

// ---------------- steady-state GEMM core (B LDS-resident) ----------------
// M=128 rows. NT = 64 or 32 cols. K = NCH*64 from kbase (into A source).
// AMODE 0: A fp32 (a32), split hi/lo.  AMODE 1: A packed uint (apk).
// acc: FM*FN facc accumulators, caller-owned (persist across calls).
template <int NT, bool BSPLIT, int AMODE, int NCH>
__device__ void gemm_core(facc* acc, unsigned short* sAh, unsigned short* sAl,
                          const unsigned short* wh, const unsigned short* wl,
                          const float* a32, const unsigned* apk, int as,
                          int kbase, int wchbase) {
  const int tid = threadIdx.x;
  const int lane = tid & 63;
  const int w = tid >> 6;
  constexpr int FM = 2;
  constexpr int FN = (NT == 32) ? 1 : 2;
  const int wm = (w >> 1) << 5;
  const int wn = (NT == 64) ? ((w & 1) << 5) : ((w & 1) << 4);
  const int lr = lane & 15;
  const int lk = (lane >> 4) << 3;

  unsigned pva[16], pvb[16];
#pragma unroll
  for (int ii = 0; ii < 16; ii++) {
    int r = ii * 8 + w;
    pva[ii] = (AMODE == 0) ? __float_as_uint(a32[(size_t)r * as + kbase + lane])
                           : aldu(&apk[(size_t)r * as + kbase + lane]);
  }
#pragma unroll
  for (int ch = 0; ch < NCH; ++ch) {
    unsigned* cur = (ch & 1) ? pvb : pva;
    unsigned* nxt = (ch & 1) ? pva : pvb;
    if (ch + 1 < NCH) {
      const int kk1 = kbase + (ch + 1) * 64;
#pragma unroll
      for (int ii = 0; ii < 16; ii++) {
        int r = ii * 8 + w;
        nxt[ii] = (AMODE == 0) ? __float_as_uint(a32[(size_t)r * as + kk1 + lane])
                               : aldu(&apk[(size_t)r * as + kk1 + lane]);
      }
    }
#pragma unroll
    for (int ii = 0; ii < 16; ii++) {
      int r = ii * 8 + w;
      unsigned p = cur[ii];
      unsigned short uh, ul;
      if (AMODE == 0) split_bf(__uint_as_float(p), uh, ul);
      else { uh = (unsigned short)(p >> 16); ul = (unsigned short)(p & 0xffffu); }
      sAh[r * LDK + lane] = uh;
      sAl[r * LDK + lane] = ul;
    }
    asm volatile("s_waitcnt lgkmcnt(0)" ::: "memory");
    __builtin_amdgcn_s_barrier();
    __builtin_amdgcn_sched_barrier(0);
    const int wch = wchbase + ch;
#pragma unroll
    for (int k32 = 0; k32 < 64; k32 += 32) {
      bfrag ah[FM], al_[FM], bhf[FN], blf[FN];
#pragma unroll
      for (int f = 0; f < FM; f++) {
        const int ao = (wm + (f << 4) + lr) * LDK + k32 + lk;
        ah[f]  = *(const bfrag*)&sAh[ao];
        al_[f] = *(const bfrag*)&sAl[ao];
      }
#pragma unroll
      for (int f = 0; f < FN; f++) {
        const int bo = (wch * NT + wn + (f << 4) + lr) * LDK + k32 + lk;
        bhf[f] = *(const bfrag*)&wh[bo];
        if constexpr (BSPLIT) blf[f] = *(const bfrag*)&wl[bo];
      }
#pragma unroll
      for (int i = 0; i < FM; i++)
#pragma unroll
        for (int j = 0; j < FN; j++) {
          acc[i * FN + j] = __builtin_amdgcn_mfma_f32_16x16x32_bf16(al_[i], bhf[j], acc[i * FN + j], 0, 0, 0);
          if constexpr (BSPLIT)
            acc[i * FN + j] = __builtin_amdgcn_mfma_f32_16x16x32_bf16(ah[i], blf[j], acc[i * FN + j], 0, 0, 0);
          acc[i * FN + j] = __builtin_amdgcn_mfma_f32_16x16x32_bf16(ah[i], bhf[j], acc[i * FN + j], 0, 0, 0);
        }
    }
    __builtin_amdgcn_sched_barrier(0);
    __builtin_amdgcn_s_barrier();
    __builtin_amdgcn_sched_barrier(0);
  }
}

// ---------------- prologue GEMM (B streamed hi/lo from global) ----------------
__device__ void gemm_pro(unsigned short* sAh, unsigned short* sAl, unsigned short* warea,
                         const float* a32,
                         const unsigned short* bh_g, const unsigned short* bl_g,
                         float* dst) {
  const int tid = threadIdx.x;
  const int lane = tid & 63;
  const int w = tid >> 6;
  const int wm = (w >> 2) << 6;
  const int wn = (w & 3) << 5;
  const int lr = lane & 15;
  const int lk = (lane >> 4) << 3;
  unsigned short* wh = warea;
  unsigned short* wl = warea + 128 * LDK;
  const facc fz = {0.f, 0.f, 0.f, 0.f};
  facc acc[4][2];
#pragma unroll
  for (int i = 0; i < 4; i++)
#pragma unroll
    for (int j = 0; j < 2; j++) acc[i][j] = fz;
  for (int ch = 0; ch < 8; ++ch) {
    const int kk0 = ch << 6;
    for (int i = tid; i < 8192; i += NTHR) {
      const int r = i >> 6, k = i & 63;
      unsigned short uh, ul;
      split_bf(a32[(size_t)r * EE + kk0 + k], uh, ul);
      sAh[r * LDK + k] = uh;
      sAl[r * LDK + k] = ul;
      wh[r * LDK + k] = bh_g[(size_t)r * EE + kk0 + k];
      wl[r * LDK + k] = bl_g[(size_t)r * EE + kk0 + k];
    }
    __syncthreads();
#pragma unroll
    for (int k32 = 0; k32 < 64; k32 += 32) {
      bfrag ah[4], al_[4], bhf[2], blf[2];
#pragma unroll
      for (int f = 0; f < 4; f++) {
        const int ao = (wm + (f << 4) + lr) * LDK + k32 + lk;
        ah[f]  = *(const bfrag*)&sAh[ao];
        al_[f] = *(const bfrag*)&sAl[ao];
      }
#pragma unroll
      for (int f = 0; f < 2; f++) {
        const int bo = (wn + (f << 4) + lr) * LDK + k32 + lk;
        bhf[f] = *(const bfrag*)&wh[bo];
        blf[f] = *(const bfrag*)&wl[bo];
      }
#pragma unroll
      for (int i = 0; i < 4; i++)
#pragma unroll
        for (int j = 0; j < 2; j++) {
          acc[i][j] = __builtin_amdgcn_mfma_f32_16x16x32_bf16(al_[i], bhf[j], acc[i][j], 0, 0, 0);
          acc[i][j] = __builtin_amdgcn_mfma_f32_16x16x32_bf16(ah[i], blf[j], acc[i][j], 0, 0, 0);
          acc[i][j] = __builtin_amdgcn_mfma_f32_16x16x32_bf16(ah[i], bhf[j], acc[i][j], 0, 0, 0);
        }
    }
    __syncthreads();
  }
  const int orow = (lane >> 4) << 2;
  const int ocol = lane & 15;
#pragma unroll
  for (int i = 0; i < 4; i++)
#pragma unroll
    for (int j = 0; j < 2; j++)
#pragma unroll
      for (int q = 0; q < 4; q++)
        dst[(size_t)(wm + (i << 4) + orow + q) * HH + (wn + (j << 4) + ocol)] = acc[i][j][q];
}

// ---------------- setup kernels ----------------
__global__ void __launch_bounds__(256) k_transpose_qp(
    const float* __restrict__ Wq, const float* __restrict__ Wp,
    unsigned short* __restrict__ wqth, unsigned short* __restrict__ wqtl,
    unsigned short* __restrict__ wpth, unsigned short* __restrict__ wptl) {
  __shared__ float tile[64 * 65];
  const int blk = blockIdx.x;
  const int mat = blk >> 6;
  const int rem = blk & 63;
  const int d = rem >> 5;
  const int rem2 = rem & 31;
  const int kt = rem2 >> 2;
  const int nt = rem2 & 3;
  const float* src = mat ? Wp : Wq;
  unsigned short* dh = mat ? wpth : wqth;
  unsigned short* dl = mat ? wptl : wqtl;
  const int tid = threadIdx.x;
  for (int i = tid; i < 4096; i += 256) {
    int kr = i >> 6, nc = i & 63;
    tile[kr * 65 + nc] = src[((size_t)d * EE + kt * 64 + kr) * HH + nt * 64 + nc];
  }
  __syncthreads();
  for (int i = tid; i < 4096; i += 256) {
    int n = i >> 6, k = i & 63;
    unsigned short hi, lo;
    split_bf(tile[k * 65 + n], hi, lo);
    size_t o = ((size_t)d * HH + nt * 64 + n) * EE + kt * 64 + k;
    dh[o] = hi; dl[o] = lo;
  }
}

__global__ void __launch_bounds__(256) k_split_w(
    const float* __restrict__ gw, const float* __restrict__ wih, const float* __restrict__ whh,
    unsigned short* __restrict__ gwh, unsigned short* __restrict__ gwl,
    unsigned short* __restrict__ wihh, unsigned short* __restrict__ wihl,
    unsigned short* __restrict__ whhh, unsigned short* __restrict__ whhl) {
  const size_t N1 = HSZ_GW, N2 = HSZ_WIH, N3 = HSZ_WHH;
  for (size_t i = (size_t)blockIdx.x * 256 + threadIdx.x; i < N1 + N2 + N3;
       i += (size_t)gridDim.x * 256) {
    float x; unsigned short *ph, *pl; size_t o;
    if (i < N1)           { o = i;           x = gw[o];  ph = gwh;  pl = gwl; }
    else if (i < N1 + N2) { o = i - N1;      x = wih[o]; ph = wihh; pl = wihl; }
    else                  { o = i - N1 - N2; x = whh[o]; ph = whhh; pl = whhl; }
    unsigned short hi, lo;
    split_bf(x, hi, lo);
    ph[o] = hi; pl[o] = lo;
  }
}

__global__ void __launch_bounds__(256) k_wst(const float* __restrict__ Ws,
                                             float* __restrict__ wst) {
  size_t i = (size_t)blockIdx.x * 256 + threadIdx.x;
  if (i >= SZ_WST) return;
  int d = (int)(i >> 16);
  int j = (int)((i >> 8) & 255);
  int k = (int)(i & 255);
  wst[i] = Ws[((size_t)d * HH + k) * HH + j];
}

// ---------------- the persistent kernel ----------------
__global__ void __launch_bounds__(NTHR, 1) pe_main(
    const float* __restrict__ qin, const float* __restrict__ pin,
    const unsigned char* __restrict__ qmask,
    const float* __restrict__ vvec, const float* __restrict__ gateb,
    const float* __restrict__ bih, const float* __restrict__ bhh,
    float* __restrict__ out,
    float* __restrict__ fws, unsigned* __restrict__ upck,
    unsigned short* __restrict__ hws, unsigned* __restrict__ bar) {
  __shared__ __align__(16) unsigned short smem[56320];  // 112.6 KB
  unsigned short* sAh = smem;            // 9216 shorts
  unsigned short* sAl = smem + 9216;     // 9216 shorts
  unsigned short* warea = smem + 18432;  // 36864 shorts (resident weights / prologue B)
  float* fsm = (float*)smem;             // phase-A / C2 scratch (aliases sAh/sAl)
  float* sv_perm   = (float*)(smem + 55296);  // 256 floats, loop-invariant v
  float* sstv_perm = (float*)(smem + 55808);  // 256 floats, state_temp

  float* qt   = fws + OFF_QT;
  float* pt   = fws + OFF_PT;
  float* gip  = fws + OFF_GIP;
  float* ghp  = fws + OFF_GHP;
  float* wst  = fws + OFF_WST;
  unsigned* attp0 = upck + UOFF_ATTP;   // parity buffers
  unsigned* xpck0 = upck + UOFF_XPACK;
  unsigned* hpack = upck + UOFF_HPACK;
  unsigned short* wqth = hws + HOFF_WQTH;
  unsigned short* wqtl = hws + HOFF_WQTL;
  unsigned short* wpth = hws + HOFF_WPTH;
  unsigned short* wptl = hws + HOFF_WPTL;
  unsigned short* gwh  = hws + HOFF_GWH;
  unsigned short* wihh = hws + HOFF_WIHH;
  unsigned short* wihl = hws + HOFF_WIHL;
  unsigned short* whhh = hws + HOFF_WHHH;
  unsigned short* whhl = hws + HOFF_WHHL;
  unsigned* flg = bar + 256;

  const int blk = blockIdx.x;
  const int tid = threadIdx.x;
  const int lane = tid & 63;
  const int w = tid >> 6;

  // role constants
  const bool isGate = (blk < 64);
  const bool isGi   = (blk >= 64 && blk < 160);
  const bool isGh   = (blk >= 160 && blk < 184);
  const int gd = blk >> 5, gct = blk & 31, coloff = gct * 32;           // gate
  const int gi_g = blk - 64, id_ = gi_g / 48, ir = gi_g % 48;           // gi
  const int int_ = ir >> 2, iks = ir & 3;
  const int gh_g = blk - 160, hd = gh_g / 12, hnt = gh_g % 12;          // gh

  // ---- prologue: q_temp / p_temp GEMMs ----
  for (int tt = blk; tt < 1840; tt += NBLK) {
    if (tt < 1600) {
      int d = tt / 800, rem = tt % 800, mt = rem >> 1, ntp = rem & 1;
      gemm_pro(sAh, sAl, warea, pin + (size_t)mt * BB * EE,
               wpth + ((size_t)d * HH + ntp * 128) * EE,
               wptl + ((size_t)d * HH + ntp * 128) * EE,
               pt + ((size_t)d * PL * BB + (size_t)mt * BB) * HH + ntp * 128);
    } else {
      int u2 = tt - 1600;
      int d = u2 / 120, rem = u2 % 120, mt = rem >> 1, ntp = rem & 1;
      gemm_pro(sAh, sAl, warea, qin + (size_t)mt * BB * EE,
               wqth + ((size_t)d * HH + ntp * 128) * EE,
               wqtl + ((size_t)d * HH + ntp * 128) * EE,
               qt + ((size_t)d * QL * BB + (size_t)mt * BB) * HH + ntp * 128);
    }
  }

  // ---- prologue: load resident weight tiles ----
  if (isGate) {                 // gate: 32 cols, full K=1024, single bf16 (64 KB)
    const unsigned short* src = gwh + (size_t)(gd * DD + coloff) * DD;
    for (int i = tid; i < 32768; i += NTHR) {
      int ch = i >> 11, n = (i >> 6) & 31, k = i & 63;
      warea[(ch * 32 + n) * LDK + k] = src[(size_t)n * DD + ch * 64 + k];
    }
  } else if (isGi) {            // gi: Wih hi/lo, NT=64, K-range 256
    const unsigned short* sh = wihh + (size_t)(id_ * G3 + int_ * 64) * DD + iks * 256;
    const unsigned short* sl = wihl + (size_t)(id_ * G3 + int_ * 64) * DD + iks * 256;
    for (int i = tid; i < 16384; i += NTHR) {
      int ch = i >> 12, n = (i >> 6) & 63, k = i & 63;
      warea[(ch * 64 + n) * LDK + k]         = sh[(size_t)n * DD + ch * 64 + k];
      warea[18432 + (ch * 64 + n) * LDK + k] = sl[(size_t)n * DD + ch * 64 + k];
    }
  } else if (isGh) {            // gh: Whh hi/lo, NT=64, K=256
    const unsigned short* sh = whhh + (size_t)(hd * G3 + hnt * 64) * HH;
    const unsigned short* sl = whhl + (size_t)(hd * G3 + hnt * 64) * HH;
    for (int i = tid; i < 16384; i += NTHR) {
      int ch = i >> 12, n = (i >> 6) & 63, k = i & 63;
      warea[(ch * 64 + n) * LDK + k]         = sh[(size_t)n * HH + ch * 64 + k];
      warea[18432 + (ch * 64 + n) * LDK + k] = sl[(size_t)n * HH + ch * 64 + k];
    }
  }

  __builtin_amdgcn_fence(__ATOMIC_RELEASE, "agent");
  gbar(bar, 1);  // publish qt/pt + residents (single grid barrier)

  const int d_ab = blk >> 7, b_ab = blk & 127;
  // loop-invariant init
  if (tid < 256) {
    sv_perm[tid] = vvec[d_ab * HH + tid];
    sstv_perm[tid] = 0.f;
  }
  const bool qmv = (tid < 64 && lane < QL) ? (qmask[lane * BB + b_ab] != 0) : false;
  __syncthreads();

  // gate: precompute pin-half accumulators for s=0
  facc pinacc[2];
  if (isGate) {
    const facc fz = {0.f, 0.f, 0.f, 0.f};
    pinacc[0] = fz; pinacc[1] = fz;
    const int t0 = gd ? (PL - 1) : 0;
    gemm_core<32, false, 0, 8>(pinacc, sAh, sAl, warea, nullptr,
                               pin + (size_t)t0 * BB * EE, nullptr, EE, 0, 0);
  }

  float hreg = 0.f;
  float* sm = fsm;            // 256
  float* slog = fsm + 512;    // 64
  float* swgt = fsm + 576;    // 64
  float* spart = fsm + 896;   // 512
  float* hrow = fsm + 1408;   // 256

  for (int s = 0; s < PL; ++s) {
    const int par = s & 1;
    unsigned* attp = attp0 + (size_t)par * 2 * BB * EE;
    unsigned* xpack = xpck0 + (size_t)par * 2 * BB * DD;
    const unsigned gen = (unsigned)(s + 1);

    // ---------- phase A: attention (all blocks; own (d,b)) ----------
    {
      const int d = d_ab, b = b_ab;
      const int t = d ? (PL - 1 - s) : s;
      if (tid < 256) {
        float ptv = __builtin_nontemporal_load(&pt[(((size_t)d * PL + t) * BB + b) * HH + tid]);
        sm[tid] = sstv_perm[tid] + ptv;
      }
      __syncthreads();
      for (int q = w; q < QL; q += 8) {
        float a = 0.f;
#pragma unroll
        for (int jj = 0; jj < 4; jj++) {
          int j = lane + jj * 64;
          a += ftanh(qt[(((size_t)d * QL + q) * BB + b) * HH + j] + sm[j]) * sv_perm[j];
        }
        for (int off = 32; off; off >>= 1) a += __shfl_down(a, off, 64);
        if (lane == 0) slog[q] = a;
      }
      __syncthreads();
      if (tid < 64) {
        float x = -3.0e38f;
        if (lane < QL) {
          x = slog[lane];
          if (qmv) x = -3.0e38f;
        }
        float mx = x;
        for (int off = 32; off; off >>= 1) mx = fmaxf(mx, __shfl_xor(mx, off, 64));
        float e = (lane < QL) ? __expf(x - mx) : 0.f;
        float sum2 = e;
        for (int off = 32; off; off >>= 1) sum2 += __shfl_xor(sum2, off, 64);
        if (lane < QL) swgt[lane] = e * __builtin_amdgcn_rcpf(sum2);
      }
      __syncthreads();
      {
        const int c = tid;  // 0..511
        float a0 = 0.f, a1 = 0.f, a2 = 0.f, a3 = 0.f;
        const float* qb = qin + (size_t)b * EE + c;
        for (int q = 0; q < QL; q += 4) {
          a0 += swgt[q]     * qb[(size_t)q * BB * EE];
          a1 += swgt[q + 1] * qb[(size_t)(q + 1) * BB * EE];
          a2 += swgt[q + 2] * qb[(size_t)(q + 2) * BB * EE];
          a3 += swgt[q + 3] * qb[(size_t)(q + 3) * BB * EE];
        }
        astu(&attp[((size_t)d * BB + b) * EE + c], packf((a0 + a1) + (a2 + a3)));
      }
      __syncthreads();  // drain attp stores
      if (tid == 0) astu(&flg[FA + d_ab * 128 + b_ab], gen);
    }

    // ---------- role phases (flag-driven) ----------
    if (isGate) {
      if (tid < 128) pollge(&flg[FA + gd * 128 + tid], gen);
      __syncthreads();
      // att half (K = 512..1023), accumulate onto pinacc
      gemm_core<32, false, 1, 8>(pinacc, sAh, sAl, warea, nullptr,
                                 nullptr, attp + (size_t)gd * BB * EE, EE, 0, 8);
      // epilogue: x = u * sigm(g + b) -> xpack
      {
        const int t = gd ? (PL - 1 - s) : s;
        const float* pin_t = pin + (size_t)t * BB * EE;
        const int wm2 = (w >> 1) << 5;
        const int wn2 = (w & 1) << 4;
        const int orow = (lane >> 4) << 2;
        const int ocol = lane & 15;
#pragma unroll
        for (int i = 0; i < 2; i++)
#pragma unroll
          for (int q = 0; q < 4; q++) {
            const int row = wm2 + (i << 4) + orow + q;
            const int gcol = coloff + wn2 + ocol;
            float uv = (gct < 16) ? pin_t[(size_t)row * EE + gcol]
                                  : unpk(aldu(&attp[((size_t)gd * BB + row) * EE + gcol - EE]));
            float x = uv * sigm(pinacc[i][q] + gateb[(size_t)gd * DD + gcol]);
            astu(&xpack[((size_t)gd * BB + row) * DD + gcol], packf(x));
          }
      }
      __syncthreads();
      if (tid == 0) astu(&flg[FG + gd * 32 + gct], gen);
      // shadow: pin-half for next step
      if (s + 1 < PL) {
        const facc fz = {0.f, 0.f, 0.f, 0.f};
        pinacc[0] = fz; pinacc[1] = fz;
        const int t2 = gd ? (PL - 2 - s) : (s + 1);
        gemm_core<32, false, 0, 8>(pinacc, sAh, sAl, warea, nullptr,
                                   pin + (size_t)t2 * BB * EE, nullptr, EE, 0, 0);
      }
    } else if (isGi) {
      if (tid < 8) pollge(&flg[FG + id_ * 32 + iks * 8 + tid], gen);
      __syncthreads();
      const facc fz = {0.f, 0.f, 0.f, 0.f};
      facc acc[4] = {fz, fz, fz, fz};
      gemm_core<64, true, 1, 4>(acc, sAh, sAl, warea, warea + 18432,
                                nullptr, xpack + (size_t)id_ * BB * DD, DD, iks * 256, 0);
      {
        const int wm2 = (w >> 1) << 5;
        const int wn2 = (w & 1) << 5;
        const int orow = (lane >> 4) << 2;
        const int ocol = lane & 15;
#pragma unroll
        for (int i = 0; i < 2; i++)
#pragma unroll
          for (int j = 0; j < 2; j++)
#pragma unroll
            for (int q = 0; q < 4; q++) {
              const int row = wm2 + (i << 4) + orow + q;
              const int col = int_ * 64 + wn2 + (j << 4) + ocol;
              ast(&gip[((size_t)(id_ * 4 + iks) * BB + row) * G3 + col], acc[i * 2 + j][q]);
            }
      }
      __syncthreads();
      if (tid == 0) astu(&flg[FI + id_ * 48 + ir], gen);
    } else if (isGh) {
      if (s > 0 && tid < 128) pollge(&flg[FC + hd * 128 + tid], (unsigned)s);
      __syncthreads();
      const facc fz = {0.f, 0.f, 0.f, 0.f};
      facc acc[4] = {fz, fz, fz, fz};
      gemm_core<64, true, 1, 4>(acc, sAh, sAl, warea, warea + 18432,
                                nullptr, hpack + (size_t)hd * BB * HH, HH, 0, 0);
      {
        const int wm2 = (w >> 1) << 5;
        const int wn2 = (w & 1) << 5;
        const int orow = (lane >> 4) << 2;
        const int ocol = lane & 15;
#pragma unroll
        for (int i = 0; i < 2; i++)
#pragma unroll
          for (int j = 0; j < 2; j++)
#pragma unroll
            for (int q = 0; q < 4; q++) {
              const int row = wm2 + (i << 4) + orow + q;
              const int col = hnt * 64 + wn2 + (j << 4) + ocol;
              ast(&ghp[((size_t)hd * BB + row) * G3 + col], acc[i * 2 + j][q]);
            }
      }
      __syncthreads();
      if (tid == 0) astu(&flg[FH + hd * 12 + hnt], gen);
    }

    // ---------- phase C2: GRU + output + state_temp GEMV ----------
    {
      if (tid < 48) pollge(&flg[FI + d_ab * 48 + tid], gen);
      else if (tid < 60) pollge(&flg[FH + d_ab * 12 + (tid - 48)], gen);
      __syncthreads();
      const int d = d_ab, b = b_ab;
      const int j = tid & 255, half = tid >> 8;
      const int t = d ? (PL - 1 - s) : s;
      const size_t rb = (size_t)d * BB + b;
      float gi3[3], gh3[3];
#pragma unroll
      for (int c3 = 0; c3 < 3; c3++) {
        float acc2 = bih[(size_t)d * G3 + c3 * HH + j];
#pragma unroll
        for (int ks = 0; ks < 4; ks++)
          acc2 += ald(&gip[((size_t)(d * 4 + ks) * BB + b) * G3 + c3 * HH + j]);
        gi3[c3] = acc2;
        gh3[c3] = ald(&ghp[rb * G3 + c3 * HH + j]) + bhh[(size_t)d * G3 + c3 * HH + j];
      }
      float r = sigm(gi3[0] + gh3[0]);
      float z = sigm(gi3[1] + gh3[1]);
      float n = ftanh(gi3[2] + r * gh3[2]);
      float hn = (1.f - z) * n + z * hreg;
      hreg = hn;
      if (half == 0) {
        out[((size_t)t * BB + b) * 512 + d * HH + j] = hn;
        astu(&hpack[rb * HH + j], packf(hn));
        hrow[j] = hn;
      }
      __syncthreads();  // drains hpack stores
      if (tid == 0) astu(&flg[FC + d_ab * 128 + b_ab], gen);
      float part = 0.f;
      const float* wr = wst + ((size_t)d * HH + j) * HH + (half << 7);
      const float* hr = hrow + (half << 7);
#pragma unroll
      for (int k = 0; k < 128; k += 4) {
        float4 w4 = *(const float4*)&wr[k];
        float4 h4 = *(const float4*)&hr[k];
        part += w4.x * h4.x + w4.y * h4.y + w4.z * h4.z + w4.w * h4.w;
      }
      spart[tid] = part;
      __syncthreads();
      if (tid < 256) sstv_perm[tid] = spart[tid] + spart[tid + 256];
      __syncthreads();
    }
  }
}

// ---------------- launch ----------------
extern "C" void kernel_launch(void* const* d_in, const int* in_sizes, int n_in,
                              void* d_out, int out_size, void* d_ws, size_t ws_size,
                              hipStream_t stream) {
  const float* qin = (const float*)d_in[0];
  const float* pin = (const float*)d_in[1];
  const unsigned char* qmask = (const unsigned char*)d_in[2];
  const float* Wq  = (const float*)d_in[3];
  const float* Wp  = (const float*)d_in[4];
  const float* Ws  = (const float*)d_in[5];
  const float* v   = (const float*)d_in[6];
  const float* gw  = (const float*)d_in[7];
  const float* gb  = (const float*)d_in[8];
  const float* wih = (const float*)d_in[9];
  const float* whh = (const float*)d_in[10];
  const float* bih = (const float*)d_in[11];
  const float* bhh = (const float*)d_in[12];
  float* out = (float*)d_out;

  char* base = (char*)d_ws;
  float* fws = (float*)base;
  unsigned* upck = (unsigned*)(base + F32_TOT * sizeof(float));
  unsigned short* hws = (unsigned short*)(base + F32_TOT * sizeof(float) + U_TOT * sizeof(unsigned));
  unsigned* bar = (unsigned*)(base + F32_TOT * sizeof(float) + U_TOT * sizeof(unsigned) +
                              H_TOT * sizeof(unsigned short));
  size_t need = F32_TOT * sizeof(float) + U_TOT * sizeof(unsigned) +
                H_TOT * sizeof(unsigned short) + 8192;
  if (ws_size < need) return;

  // zero h-state + barrier slots + flags (re-runs on every graph replay)
  hipMemsetAsync(upck + UOFF_HPACK, 0, (size_t)2 * BB * HH * sizeof(unsigned), stream);
  hipMemsetAsync(bar, 0, 4096, stream);

  k_transpose_qp<<<128, 256, 0, stream>>>(Wq, Wp,
      hws + HOFF_WQTH, hws + HOFF_WQTL, hws + HOFF_WPTH, hws + HOFF_WPTL);
  k_split_w<<<1024, 256, 0, stream>>>(gw, wih, whh,
      hws + HOFF_GWH, hws + HOFF_GWL, hws + HOFF_WIHH, hws + HOFF_WIHL,
      hws + HOFF_WHHH, hws + HOFF_WHHL);
  k_wst<<<(int)((SZ_WST + 255) / 256), 256, 0, stream>>>(Ws, fws + OFF_WST);
  pe_main<<<NBLK, NTHR, 0, stream>>>(qin, pin, qmask, v, gb, bih, bhh, out,
                                     fws, upck, hws, bar);
}

// Round 8
// 20536.919 us; speedup vs baseline: 7.8793x; 1.2440x over previous
//
#include <hip/hip_runtime.h>

// ---------------- problem constants ----------------
#define PL 400
#define QL 60
#define BB 128
#define EE 512
#define HH 256
#define DD 1024
#define G3 768
#define NBLK 256
#define NTHR 512
#define LDK 72   // padded K stride (shorts) for LDS B tiles

typedef __attribute__((ext_vector_type(8))) short bfrag;
typedef __attribute__((ext_vector_type(4))) float facc;
typedef __attribute__((ext_vector_type(4))) unsigned uintx4;

// ---------------- bf16 / math helpers ----------------
__device__ __forceinline__ unsigned short f2bf(float x) {
  unsigned u = __float_as_uint(x);
  return (unsigned short)((u + 0x7fffu + ((u >> 16) & 1u)) >> 16);
}
__device__ __forceinline__ float bf2f(unsigned short h) {
  return __uint_as_float(((unsigned)h) << 16);
}
__device__ __forceinline__ void split_bf(float x, unsigned short& hi, unsigned short& lo) {
  hi = f2bf(x);
  lo = f2bf(x - bf2f(hi));
}
__device__ __forceinline__ unsigned packf(float x) {
  unsigned short hi, lo;
  split_bf(x, hi, lo);
  return ((unsigned)hi << 16) | lo;
}
__device__ __forceinline__ float unpk(unsigned p) {
  return bf2f((unsigned short)(p >> 16)) + bf2f((unsigned short)(p & 0xffffu));
}
__device__ __forceinline__ float sigm(float x) {
  return __builtin_amdgcn_rcpf(1.f + __expf(-x));
}
__device__ __forceinline__ float ftanh(float x) {
  float xc = fminf(fmaxf(x, -10.f), 10.f);
  float t = __expf(2.f * xc);
  return (t - 1.f) * __builtin_amdgcn_rcpf(t + 1.f);
}

// ---------------- agent-scope relaxed atomics (MALL-coherent) ----------------
__device__ __forceinline__ float ald(const float* p) {
  return __hip_atomic_load((float*)p, __ATOMIC_RELAXED, __HIP_MEMORY_SCOPE_AGENT);
}
__device__ __forceinline__ void ast(float* p, float v) {
  __hip_atomic_store(p, v, __ATOMIC_RELAXED, __HIP_MEMORY_SCOPE_AGENT);
}
__device__ __forceinline__ unsigned aldu(const unsigned* p) {
  return __hip_atomic_load((unsigned*)p, __ATOMIC_RELAXED, __HIP_MEMORY_SCOPE_AGENT);
}
__device__ __forceinline__ void astu(unsigned* p, unsigned v) {
  __hip_atomic_store(p, v, __ATOMIC_RELAXED, __HIP_MEMORY_SCOPE_AGENT);
}
__device__ __forceinline__ unsigned long long aldull(const unsigned long long* p) {
  return __hip_atomic_load((unsigned long long*)p, __ATOMIC_RELAXED, __HIP_MEMORY_SCOPE_AGENT);
}
__device__ __forceinline__ void pollge(unsigned* f, unsigned tgt) {
  unsigned sp = 0;
  while (aldu(f) < tgt) {
    __builtin_amdgcn_s_sleep(1);
    if (++sp > (1u << 26)) break;  // hang bailout
  }
}

// ---------------- ws layout ----------------
// fp32 region
constexpr size_t SZ_QT  = (size_t)2 * QL * BB * HH;
constexpr size_t SZ_PT  = (size_t)2 * PL * BB * HH;
constexpr size_t SZ_GIP = (size_t)2 * 4 * BB * G3;  // gi partials (k-split 4)
constexpr size_t SZ_GHP = (size_t)2 * BB * G3;      // gh final
constexpr size_t SZ_WST = (size_t)2 * HH * HH;      // Ws transposed
constexpr size_t OFF_QT  = 0;
constexpr size_t OFF_PT  = OFF_QT + SZ_QT;
constexpr size_t OFF_GIP = OFF_PT + SZ_PT;
constexpr size_t OFF_GHP = OFF_GIP + SZ_GIP;
constexpr size_t OFF_WST = OFF_GHP + SZ_GHP;
constexpr size_t F32_TOT = OFF_WST + SZ_WST;
// uint region (packed hi/lo bf16); attp & xpack parity double-buffered
constexpr size_t UOFF_ATTP  = 0;                                    // [2][d][b][512]
constexpr size_t UOFF_XPACK = UOFF_ATTP + (size_t)2 * 2 * BB * EE;  // [2][d][b][1024]
constexpr size_t UOFF_HPACK = UOFF_XPACK + (size_t)2 * 2 * BB * DD; // [d][b][256]
constexpr size_t U_TOT      = UOFF_HPACK + (size_t)2 * BB * HH;
// bf16 (ushort) region
constexpr size_t HSZ_WQT = (size_t)2 * HH * EE;
constexpr size_t HSZ_GW  = (size_t)2 * DD * DD;
constexpr size_t HSZ_WIH = (size_t)2 * G3 * DD;
constexpr size_t HSZ_WHH = (size_t)2 * G3 * HH;
constexpr size_t HOFF_WQTH = 0;
constexpr size_t HOFF_WQTL = HOFF_WQTH + HSZ_WQT;
constexpr size_t HOFF_WPTH = HOFF_WQTL + HSZ_WQT;
constexpr size_t HOFF_WPTL = HOFF_WPTH + HSZ_WQT;
constexpr size_t HOFF_GWH  = HOFF_WPTL + HSZ_WQT;
constexpr size_t HOFF_GWL  = HOFF_GWH + HSZ_GW;
constexpr size_t HOFF_WIHH = HOFF_GWL + HSZ_GW;
constexpr size_t HOFF_WIHL = HOFF_WIHH + HSZ_WIH;
constexpr size_t HOFF_WHHH = HOFF_WIHL + HSZ_WIH;
constexpr size_t HOFF_WHHL = HOFF_WHHH + HSZ_WHH;
constexpr size_t HOFF_QIN16 = HOFF_WHHL + HSZ_WHH;   // bf16 copy of q_input
constexpr size_t H_TOT      = HOFF_QIN16 + (size_t)QL * BB * EE;

// flag indices (uints, after the 256 prologue-barrier slots)
#define FA 0     // [d*128+b]   att done, value s+1
#define FG 256   // [d*32+ct]   gate done
#define FI 320   // [d*48+r]    gi done
#define FH 416   // [d*12+nt]   gh done
#define FC 440   // [d*128+b]   C2/hpack done

// ---------------- prologue grid barrier (flat all-poll) ----------------
__device__ __forceinline__ void gbar(unsigned* slots, unsigned gen) {
  asm volatile("" ::: "memory");
  __syncthreads();
  if (threadIdx.x == 0)
    __hip_atomic_store(&slots[blockIdx.x], gen, __ATOMIC_RELAXED, __HIP_MEMORY_SCOPE_AGENT);
  if (threadIdx.x < NBLK) pollge(&slots[threadIdx.x], gen);
  __syncthreads();
  asm volatile("" ::: "memory");
}

// ---------------- direct-A, barrier-free steady-state GEMM ----------------
// Wave w owns rows [w*16, w*16+16); FM=1, FN=NT/16 col fragments.
// A loaded straight into MFMA fragment layout (lane: row=w*16+(l&15),
// k-slice=(l>>4)*8, 8 contiguous elems). No LDS for A, no block barriers.
// ASRC 0: packed-uint source via 64-bit agent atomics (cross-block data).
// ASRC 1: plain fp32 source (read-only input), split hi/lo in regs.
// B resident in LDS (wh / wl), chunk-major at wchbase.
template <int NT, bool BSPLIT, int NCH, int ASRC>
__device__ void gemm_direct(facc* acc,
                            const unsigned short* wh, const unsigned short* wl,
                            const unsigned* apk, const float* a32, int as,
                            int kbase, int wchbase) {
  const int tid = threadIdx.x;
  const int lane = tid & 63;
  const int w = tid >> 6;
  constexpr int FN = NT / 16;
  const int lr = lane & 15;
  const int lk = (lane >> 4) << 3;
  const int row = (w << 4) + lr;

#pragma unroll 2
  for (int ch = 0; ch < NCH; ++ch) {
    const int kk = kbase + (ch << 6);
#pragma unroll
    for (int k32 = 0; k32 < 64; k32 += 32) {
      const int ko = kk + k32 + lk;
      bfrag ah, al_;
      {
        unsigned hu[4], lu[4];
        if constexpr (ASRC == 0) {
          const unsigned long long* src =
              (const unsigned long long*)(apk + (size_t)row * as + ko);
          unsigned long long d0 = aldull(src + 0);
          unsigned long long d1 = aldull(src + 1);
          unsigned long long d2 = aldull(src + 2);
          unsigned long long d3 = aldull(src + 3);
          unsigned p0 = (unsigned)d0, p1 = (unsigned)(d0 >> 32);
          unsigned p2 = (unsigned)d1, p3 = (unsigned)(d1 >> 32);
          unsigned p4 = (unsigned)d2, p5 = (unsigned)(d2 >> 32);
          unsigned p6 = (unsigned)d3, p7 = (unsigned)(d3 >> 32);
          hu[0] = (p0 >> 16) | (p1 & 0xffff0000u);  lu[0] = (p0 & 0xffffu) | (p1 << 16);
          hu[1] = (p2 >> 16) | (p3 & 0xffff0000u);  lu[1] = (p2 & 0xffffu) | (p3 << 16);
          hu[2] = (p4 >> 16) | (p5 & 0xffff0000u);  lu[2] = (p4 & 0xffffu) | (p5 << 16);
          hu[3] = (p6 >> 16) | (p7 & 0xffff0000u);  lu[3] = (p6 & 0xffffu) | (p7 << 16);
        } else {
          const float* src = a32 + (size_t)row * as + ko;
          float4 v0 = *(const float4*)src;
          float4 v1 = *(const float4*)(src + 4);
          unsigned short h0, l0, h1, l1;
          split_bf(v0.x, h0, l0); split_bf(v0.y, h1, l1);
          hu[0] = h0 | ((unsigned)h1 << 16); lu[0] = l0 | ((unsigned)l1 << 16);
          split_bf(v0.z, h0, l0); split_bf(v0.w, h1, l1);
          hu[1] = h0 | ((unsigned)h1 << 16); lu[1] = l0 | ((unsigned)l1 << 16);
          split_bf(v1.x, h0, l0); split_bf(v1.y, h1, l1);
          hu[2] = h0 | ((unsigned)h1 << 16); lu[2] = l0 | ((unsigned)l1 << 16);
          split_bf(v1.z, h0, l0); split_bf(v1.w, h1, l1);
          hu[3] = h0 | ((unsigned)h1 << 16); lu[3] = l0 | ((unsigned)l1 << 16);
        }
        uintx4 hv = {hu[0], hu[1], hu[2], hu[3]};
        uintx4 lv = {lu[0], lu[1], lu[2], lu[3]};
        ah  = __builtin_bit_cast(bfrag, hv);
        al_ = __builtin_bit_cast(bfrag, lv);
      }
      bfrag bhf[FN], blf[FN];
#pragma unroll
      for (int f = 0; f < FN; f++) {
        const int bo = ((wchbase + ch) * NT + (f << 4) + lr) * LDK + k32 + lk;
        bhf[f] = *(const bfrag*)&wh[bo];
        if constexpr (BSPLIT) blf[f] = *(const bfrag*)&wl[bo];
      }
#pragma unroll
      for (int j = 0; j < FN; j++) {
        acc[j] = __builtin_amdgcn_mfma_f32_16x16x32_bf16(al_, bhf[j], acc[j], 0, 0, 0);
        if constexpr (BSPLIT)
          acc[j] = __builtin_amdgcn_mfma_f32_16x16x32_bf16(ah, blf[j], acc[j], 0, 0, 0);
        acc[j] = __builtin_amdgcn_mfma_f32_16x16x32_bf16(ah, bhf[j], acc[j], 0, 0, 0);
      }
    }
  }
}

// ---------------- prologue GEMM (LDS-staged, block-synchronous) ----------------
__device__ void gemm_pro(unsigned short* sAh, unsigned short* sAl, unsigned short* warea,
                         const float* a32,
                         const unsigned short* bh_g, const unsigned short* bl_g,
                         float* dst) {
  const int tid = threadIdx.x;
  const int lane = tid & 63;
  const int w = tid >> 6;
  const int wm = (w >> 2) << 6;
  const int wn = (w & 3) << 5;
  const int lr = lane & 15;
  const int lk = (lane >> 4) << 3;
  unsigned short* wh = warea;
  unsigned short* wl = warea + 128 * LDK;
  const facc fz = {0.f, 0.f, 0.f, 0.f};
  facc acc[4][2];
#pragma unroll
  for (int i = 0; i < 4; i++)
#pragma unroll
    for (int j = 0; j < 2; j++) acc[i][j] = fz;
  for (int ch = 0; ch < 8; ++ch) {
    const int kk0 = ch << 6;
    for (int i = tid; i < 8192; i += NTHR) {
      const int r = i >> 6, k = i & 63;
      unsigned short uh, ul;
      split_bf(a32[(size_t)r * EE + kk0 + k], uh, ul);
      sAh[r * LDK + k] = uh;
      sAl[r * LDK + k] = ul;
      wh[r * LDK + k] = bh_g[(size_t)r * EE + kk0 + k];
      wl[r * LDK + k] = bl_g[(size_t)r * EE + kk0 + k];
    }
    __syncthreads();
#pragma unroll
    for (int k32 = 0; k32 < 64; k32 += 32) {
      bfrag ah[4], al_[4], bhf[2], blf[2];
#pragma unroll
      for (int f = 0; f < 4; f++) {
        const int ao = (wm + (f << 4) + lr) * LDK + k32 + lk;
        ah[f]  = *(const bfrag*)&sAh[ao];
        al_[f] = *(const bfrag*)&sAl[ao];
      }
#pragma unroll
      for (int f = 0; f < 2; f++) {
        const int bo = (wn + (f << 4) + lr) * LDK + k32 + lk;
        bhf[f] = *(const bfrag*)&wh[bo];
        blf[f] = *(const bfrag*)&wl[bo];
      }
#pragma unroll
      for (int i = 0; i < 4; i++)
#pragma unroll
        for (int j = 0; j < 2; j++) {
          acc[i][j] = __builtin_amdgcn_mfma_f32_16x16x32_bf16(al_[i], bhf[j], acc[i][j], 0, 0, 0);
          acc[i][j] = __builtin_amdgcn_mfma_f32_16x16x32_bf16(ah[i], blf[j], acc[i][j], 0, 0, 0);
          acc[i][j] = __builtin_amdgcn_mfma_f32_16x16x32_bf16(ah[i], bhf[j], acc[i][j], 0, 0, 0);
        }
    }
    __syncthreads();
  }
  const int orow = (lane >> 4) << 2;
  const int ocol = lane & 15;
#pragma unroll
  for (int i = 0; i < 4; i++)
#pragma unroll
    for (int j = 0; j < 2; j++)
#pragma unroll
      for (int q = 0; q < 4; q++)
        dst[(size_t)(wm + (i << 4) + orow + q) * HH + (wn + (j << 4) + ocol)] = acc[i][j][q];
}

// ---------------- setup kernels ----------------
__global__ void __launch_bounds__(256) k_transpose_qp(
    const float* __restrict__ Wq, const float* __restrict__ Wp,
    unsigned short* __restrict__ wqth, unsigned short* __restrict__ wqtl,
    unsigned short* __restrict__ wpth, unsigned short* __restrict__ wptl) {
  __shared__ float tile[64 * 65];
  const int blk = blockIdx.x;
  const int mat = blk >> 6;
  const int rem = blk & 63;
  const int d = rem >> 5;
  const int rem2 = rem & 31;
  const int kt = rem2 >> 2;
  const int nt = rem2 & 3;
  const float* src = mat ? Wp : Wq;
  unsigned short* dh = mat ? wpth : wqth;
  unsigned short* dl = mat ? wptl : wqtl;
  const int tid = threadIdx.x;
  for (int i = tid; i < 4096; i += 256) {
    int kr = i >> 6, nc = i & 63;
    tile[kr * 65 + nc] = src[((size_t)d * EE + kt * 64 + kr) * HH + nt * 64 + nc];
  }
  __syncthreads();
  for (int i = tid; i < 4096; i += 256) {
    int n = i >> 6, k = i & 63;
    unsigned short hi, lo;
    split_bf(tile[k * 65 + n], hi, lo);
    size_t o = ((size_t)d * HH + nt * 64 + n) * EE + kt * 64 + k;
    dh[o] = hi; dl[o] = lo;
  }
}

__global__ void __launch_bounds__(256) k_split_w(
    const float* __restrict__ gw, const float* __restrict__ wih, const float* __restrict__ whh,
    unsigned short* __restrict__ gwh, unsigned short* __restrict__ gwl,
    unsigned short* __restrict__ wihh, unsigned short* __restrict__ wihl,
    unsigned short* __restrict__ whhh, unsigned short* __restrict__ whhl) {
  const size_t N1 = HSZ_GW, N2 = HSZ_WIH, N3 = HSZ_WHH;
  for (size_t i = (size_t)blockIdx.x * 256 + threadIdx.x; i < N1 + N2 + N3;
       i += (size_t)gridDim.x * 256) {
    float x; unsigned short *ph, *pl; size_t o;
    if (i < N1)           { o = i;           x = gw[o];  ph = gwh;  pl = gwl; }
    else if (i < N1 + N2) { o = i - N1;      x = wih[o]; ph = wihh; pl = wihl; }
    else                  { o = i - N1 - N2; x = whh[o]; ph = whhh; pl = whhl; }
    unsigned short hi, lo;
    split_bf(x, hi, lo);
    ph[o] = hi; pl[o] = lo;
  }
}

__global__ void __launch_bounds__(256) k_wst_qin(const float* __restrict__ Ws,
                                                 float* __restrict__ wst,
                                                 const float* __restrict__ qin,
                                                 unsigned short* __restrict__ qin16) {
  const size_t NQ = (size_t)QL * BB * EE;
  for (size_t i = (size_t)blockIdx.x * 256 + threadIdx.x; i < SZ_WST + NQ;
       i += (size_t)gridDim.x * 256) {
    if (i < SZ_WST) {
      int d = (int)(i >> 16);
      int j = (int)((i >> 8) & 255);
      int k = (int)(i & 255);
      wst[i] = Ws[((size_t)d * HH + k) * HH + j];
    } else {
      size_t o = i - SZ_WST;
      qin16[o] = f2bf(qin[o]);
    }
  }
}

// ---------------- the persistent kernel ----------------
__global__ void __launch_bounds__(NTHR, 1) pe_main(
    const float* __restrict__ qin, const float* __restrict__ pin,
    const unsigned char* __restrict__ qmask,
    const float* __restrict__ vvec, const float* __restrict__ gateb,
    const float* __restrict__ bih, const float* __restrict__ bhh,
    float* __restrict__ out,
    float* __restrict__ fws, unsigned* __restrict__ upck,
    unsigned short* __restrict__ hws, unsigned* __restrict__ bar) {
  __shared__ __align__(16) unsigned short smem[56320];  // 112.6 KB
  unsigned short* sAh = smem;            // prologue A staging
  unsigned short* sAl = smem + 9216;
  unsigned short* warea = smem + 18432;  // 36864 shorts: resident weights / prologue B
  float* fsm = (float*)smem;             // phase-A / C2 scratch (aliases sAh/sAl)
  float* sv_perm   = (float*)(smem + 55296);  // 256 floats, loop-invariant v
  float* sstv_perm = (float*)(smem + 55808);  // 256 floats, state_temp

  float* qt   = fws + OFF_QT;
  float* pt   = fws + OFF_PT;
  float* gip  = fws + OFF_GIP;
  float* ghp  = fws + OFF_GHP;
  float* wst  = fws + OFF_WST;
  unsigned* attp0 = upck + UOFF_ATTP;
  unsigned* xpck0 = upck + UOFF_XPACK;
  unsigned* hpack = upck + UOFF_HPACK;
  unsigned short* wqth = hws + HOFF_WQTH;
  unsigned short* wqtl = hws + HOFF_WQTL;
  unsigned short* wpth = hws + HOFF_WPTH;
  unsigned short* wptl = hws + HOFF_WPTL;
  unsigned short* gwh  = hws + HOFF_GWH;
  unsigned short* wihh = hws + HOFF_WIHH;
  unsigned short* wihl = hws + HOFF_WIHL;
  unsigned short* whhh = hws + HOFF_WHHH;
  unsigned short* whhl = hws + HOFF_WHHL;
  const unsigned short* qin16 = hws + HOFF_QIN16;
  unsigned* flg = bar + 256;

  const int blk = blockIdx.x;
  const int tid = threadIdx.x;
  const int lane = tid & 63;
  const int w = tid >> 6;

  // role constants
  const bool isGate = (blk < 64);
  const bool isGi   = (blk >= 64 && blk < 160);
  const bool isGh   = (blk >= 160 && blk < 184);
  const int gd = blk >> 5, gct = blk & 31, coloff = gct * 32;           // gate
  const int gi_g = blk - 64, id_ = gi_g / 48, ir = gi_g % 48;           // gi
  const int int_ = ir >> 2, iks = ir & 3;
  const int gh_g = blk - 160, hd = gh_g / 12, hnt = gh_g % 12;          // gh

  // ---- prologue: q_temp / p_temp GEMMs ----
  for (int tt = blk; tt < 1840; tt += NBLK) {
    if (tt < 1600) {
      int d = tt / 800, rem = tt % 800, mt = rem >> 1, ntp = rem & 1;
      gemm_pro(sAh, sAl, warea, pin + (size_t)mt * BB * EE,
               wpth + ((size_t)d * HH + ntp * 128) * EE,
               wptl + ((size_t)d * HH + ntp * 128) * EE,
               pt + ((size_t)d * PL * BB + (size_t)mt * BB) * HH + ntp * 128);
    } else {
      int u2 = tt - 1600;
      int d = u2 / 120, rem = u2 % 120, mt = rem >> 1, ntp = rem & 1;
      gemm_pro(sAh, sAl, warea, qin + (size_t)mt * BB * EE,
               wqth + ((size_t)d * HH + ntp * 128) * EE,
               wqtl + ((size_t)d * HH + ntp * 128) * EE,
               qt + ((size_t)d * QL * BB + (size_t)mt * BB) * HH + ntp * 128);
    }
  }

  // ---- prologue: load resident weight tiles (chunk-major, LDK-padded) ----
  if (isGate) {                 // gate: 32 cols, full K=1024, single bf16 (~72 KB w/pad... 64 KB data)
    const unsigned short* src = gwh + (size_t)(gd * DD + coloff) * DD;
    for (int i = tid; i < 32768; i += NTHR) {
      int ch = i >> 11, n = (i >> 6) & 31, k = i & 63;
      warea[(ch * 32 + n) * LDK + k] = src[(size_t)n * DD + ch * 64 + k];
    }
  } else if (isGi) {            // gi: Wih hi/lo, NT=64, K-range 256
    const unsigned short* sh = wihh + (size_t)(id_ * G3 + int_ * 64) * DD + iks * 256;
    const unsigned short* sl = wihl + (size_t)(id_ * G3 + int_ * 64) * DD + iks * 256;
    for (int i = tid; i < 16384; i += NTHR) {
      int ch = i >> 12, n = (i >> 6) & 63, k = i & 63;
      warea[(ch * 64 + n) * LDK + k]         = sh[(size_t)n * DD + ch * 64 + k];
      warea[18432 + (ch * 64 + n) * LDK + k] = sl[(size_t)n * DD + ch * 64 + k];
    }
  } else if (isGh) {            // gh: Whh hi/lo, NT=64, K=256
    const unsigned short* sh = whhh + (size_t)(hd * G3 + hnt * 64) * HH;
    const unsigned short* sl = whhl + (size_t)(hd * G3 + hnt * 64) * HH;
    for (int i = tid; i < 16384; i += NTHR) {
      int ch = i >> 12, n = (i >> 6) & 63, k = i & 63;
      warea[(ch * 64 + n) * LDK + k]         = sh[(size_t)n * HH + ch * 64 + k];
      warea[18432 + (ch * 64 + n) * LDK + k] = sl[(size_t)n * HH + ch * 64 + k];
    }
  }

  __builtin_amdgcn_fence(__ATOMIC_RELEASE, "agent");
  gbar(bar, 1);  // publish qt/pt + residents

  const int d_ab = blk >> 7, b_ab = blk & 127;
  if (tid < 256) {
    sv_perm[tid] = vvec[d_ab * HH + tid];
    sstv_perm[tid] = 0.f;
  }
  const bool qmv = (tid < 64 && lane < QL) ? (qmask[lane * BB + b_ab] != 0) : false;
  __syncthreads();

  // gate: precompute pin-half accumulators for s=0 (fp32 A, hi/lo split)
  facc pinacc[2];
  if (isGate) {
    const facc fz = {0.f, 0.f, 0.f, 0.f};
    pinacc[0] = fz; pinacc[1] = fz;
    const int t0 = gd ? (PL - 1) : 0;
    gemm_direct<32, false, 8, 1>(pinacc, warea, nullptr,
                                 nullptr, pin + (size_t)t0 * BB * EE, EE, 0, 0);
  }

  float hreg = 0.f;
  float* sm = fsm;            // 256
  float* slog = fsm + 512;    // 64
  float* swgt = fsm + 576;    // 64
  float* spart = fsm + 896;   // 512
  float* hrow = fsm + 1408;   // 256

  for (int s = 0; s < PL; ++s) {
    const int par = s & 1;
    unsigned* attp = attp0 + (size_t)par * 2 * BB * EE;
    unsigned* xpack = xpck0 + (size_t)par * 2 * BB * DD;
    const unsigned gen = (unsigned)(s + 1);

    // ---------- phase A: attention (all blocks; own (d,b)) ----------
    {
      const int d = d_ab, b = b_ab;
      const int t = d ? (PL - 1 - s) : s;
      if (tid < 256) {
        float ptv = __builtin_nontemporal_load(&pt[(((size_t)d * PL + t) * BB + b) * HH + tid]);
        sm[tid] = sstv_perm[tid] + ptv;
      }
      __syncthreads();
      for (int q = w; q < QL; q += 8) {
        float a = 0.f;
#pragma unroll
        for (int jj = 0; jj < 4; jj++) {
          int j = lane + jj * 64;
          a += ftanh(qt[(((size_t)d * QL + q) * BB + b) * HH + j] + sm[j]) * sv_perm[j];
        }
        for (int off = 32; off; off >>= 1) a += __shfl_down(a, off, 64);
        if (lane == 0) slog[q] = a;
      }
      __syncthreads();
      if (tid < 64) {
        float x = -3.0e38f;
        if (lane < QL) {
          x = slog[lane];
          if (qmv) x = -3.0e38f;
        }
        float mx = x;
        for (int off = 32; off; off >>= 1) mx = fmaxf(mx, __shfl_xor(mx, off, 64));
        float e = (lane < QL) ? __expf(x - mx) : 0.f;
        float sum2 = e;
        for (int off = 32; off; off >>= 1) sum2 += __shfl_xor(sum2, off, 64);
        if (lane < QL) swgt[lane] = e * __builtin_amdgcn_rcpf(sum2);
      }
      __syncthreads();
      {
        const int c = tid;  // 0..511; qin16 is L2-resident (bf16)
        float a0 = 0.f, a1 = 0.f, a2 = 0.f, a3 = 0.f;
        const unsigned short* qb = qin16 + (size_t)b * EE + c;
        for (int q = 0; q < QL; q += 4) {
          a0 += swgt[q]     * bf2f(qb[(size_t)q * BB * EE]);
          a1 += swgt[q + 1] * bf2f(qb[(size_t)(q + 1) * BB * EE]);
          a2 += swgt[q + 2] * bf2f(qb[(size_t)(q + 2) * BB * EE]);
          a3 += swgt[q + 3] * bf2f(qb[(size_t)(q + 3) * BB * EE]);
        }
        astu(&attp[((size_t)d * BB + b) * EE + c], packf((a0 + a1) + (a2 + a3)));
      }
      __syncthreads();  // drain attp stores
      if (tid == 0) astu(&flg[FA + d_ab * 128 + b_ab], gen);
    }

    // ---------- role phases (flag-driven, barrier-free GEMMs) ----------
    const int orow = (lane >> 4) << 2;
    const int ocol = lane & 15;
    const int rbase = w << 4;

    if (isGate) {
      if (tid < 128) pollge(&flg[FA + gd * 128 + tid], gen);
      __syncthreads();
      // att half (K = 512..1023 of u), accumulate onto pinacc; B chunks 8..15
      gemm_direct<32, false, 8, 0>(pinacc, warea, nullptr,
                                   attp + (size_t)gd * BB * EE, nullptr, EE, 0, 8);
      // epilogue: x = u * sigm(g + b) -> xpack
      {
        const int t = gd ? (PL - 1 - s) : s;
        const float* pin_t = pin + (size_t)t * BB * EE;
#pragma unroll
        for (int i = 0; i < 2; i++)
#pragma unroll
          for (int q = 0; q < 4; q++) {
            const int row = rbase + orow + q;
            const int gcol = coloff + (i << 4) + ocol;
            float uv = (gct < 16) ? pin_t[(size_t)row * EE + gcol]
                                  : unpk(aldu(&attp[((size_t)gd * BB + row) * EE + gcol - EE]));
            float x = uv * sigm(pinacc[i][q] + gateb[(size_t)gd * DD + gcol]);
            astu(&xpack[((size_t)gd * BB + row) * DD + gcol], packf(x));
          }
      }
      __syncthreads();
      if (tid == 0) astu(&flg[FG + gd * 32 + gct], gen);
      // shadow: pin-half for next step (off critical path)
      if (s + 1 < PL) {
        const facc fz = {0.f, 0.f, 0.f, 0.f};
        pinacc[0] = fz; pinacc[1] = fz;
        const int t2 = gd ? (PL - 2 - s) : (s + 1);
        gemm_direct<32, false, 8, 1>(pinacc, warea, nullptr,
                                     nullptr, pin + (size_t)t2 * BB * EE, EE, 0, 0);
      }
    } else if (isGi) {
      if (tid < 8) pollge(&flg[FG + id_ * 32 + iks * 8 + tid], gen);
      __syncthreads();
      const facc fz = {0.f, 0.f, 0.f, 0.f};
      facc acc[4] = {fz, fz, fz, fz};
      gemm_direct<64, true, 4, 0>(acc, warea, warea + 18432,
                                  xpack + (size_t)id_ * BB * DD, nullptr, DD, iks * 256, 0);
#pragma unroll
      for (int j = 0; j < 4; j++)
#pragma unroll
        for (int q = 0; q < 4; q++) {
          const int row = rbase + orow + q;
          const int col = int_ * 64 + (j << 4) + ocol;
          ast(&gip[((size_t)(id_ * 4 + iks) * BB + row) * G3 + col], acc[j][q]);
        }
      __syncthreads();
      if (tid == 0) astu(&flg[FI + id_ * 48 + ir], gen);
    } else if (isGh) {
      if (s > 0 && tid < 128) pollge(&flg[FC + hd * 128 + tid], (unsigned)s);
      __syncthreads();
      const facc fz = {0.f, 0.f, 0.f, 0.f};
      facc acc[4] = {fz, fz, fz, fz};
      gemm_direct<64, true, 4, 0>(acc, warea, warea + 18432,
                                  hpack + (size_t)hd * BB * HH, nullptr, HH, 0, 0);
#pragma unroll
      for (int j = 0; j < 4; j++)
#pragma unroll
        for (int q = 0; q < 4; q++) {
          const int row = rbase + orow + q;
          const int col = hnt * 64 + (j << 4) + ocol;
          ast(&ghp[((size_t)hd * BB + row) * G3 + col], acc[j][q]);
        }
      __syncthreads();
      if (tid == 0) astu(&flg[FH + hd * 12 + hnt], gen);
    }

    // ---------- phase C2: GRU + output + state_temp GEMV ----------
    {
      if (tid < 48) pollge(&flg[FI + d_ab * 48 + tid], gen);
      else if (tid < 60) pollge(&flg[FH + d_ab * 12 + (tid - 48)], gen);
      __syncthreads();
      const int d = d_ab, b = b_ab;
      const int j = tid & 255, half = tid >> 8;
      const int t = d ? (PL - 1 - s) : s;
      const size_t rb = (size_t)d * BB + b;
      float gi3[3], gh3[3];
#pragma unroll
      for (int c3 = 0; c3 < 3; c3++) {
        float acc2 = bih[(size_t)d * G3 + c3 * HH + j];
#pragma unroll
        for (int ks = 0; ks < 4; ks++)
          acc2 += ald(&gip[((size_t)(d * 4 + ks) * BB + b) * G3 + c3 * HH + j]);
        gi3[c3] = acc2;
        gh3[c3] = ald(&ghp[rb * G3 + c3 * HH + j]) + bhh[(size_t)d * G3 + c3 * HH + j];
      }
      float r = sigm(gi3[0] + gh3[0]);
      float z = sigm(gi3[1] + gh3[1]);
      float n = ftanh(gi3[2] + r * gh3[2]);
      float hn = (1.f - z) * n + z * hreg;
      hreg = hn;
      if (half == 0) {
        __builtin_nontemporal_store(hn, &out[((size_t)t * BB + b) * 512 + d * HH + j]);
        astu(&hpack[rb * HH + j], packf(hn));
        hrow[j] = hn;
      }
      __syncthreads();  // drains hpack/out stores
      if (tid == 0) astu(&flg[FC + d_ab * 128 + b_ab], gen);
      float part = 0.f;
      const float* wr = wst + ((size_t)d * HH + j) * HH + (half << 7);
      const float* hr = hrow + (half << 7);
#pragma unroll
      for (int k = 0; k < 128; k += 4) {
        float4 w4 = *(const float4*)&wr[k];
        float4 h4 = *(const float4*)&hr[k];
        part += w4.x * h4.x + w4.y * h4.y + w4.z * h4.z + w4.w * h4.w;
      }
      spart[tid] = part;
      __syncthreads();
      if (tid < 256) sstv_perm[tid] = spart[tid] + spart[tid + 256];
      __syncthreads();
    }
  }
}

// ---------------- launch ----------------
extern "C" void kernel_launch(void* const* d_in, const int* in_sizes, int n_in,
                              void* d_out, int out_size, void* d_ws, size_t ws_size,
                              hipStream_t stream) {
  const float* qin = (const float*)d_in[0];
  const float* pin = (const float*)d_in[1];
  const unsigned char* qmask = (const unsigned char*)d_in[2];
  const float* Wq  = (const float*)d_in[3];
  const float* Wp  = (const float*)d_in[4];
  const float* Ws  = (const float*)d_in[5];
  const float* v   = (const float*)d_in[6];
  const float* gw  = (const float*)d_in[7];
  const float* gb  = (const float*)d_in[8];
  const float* wih = (const float*)d_in[9];
  const float* whh = (const float*)d_in[10];
  const float* bih = (const float*)d_in[11];
  const float* bhh = (const float*)d_in[12];
  float* out = (float*)d_out;

  char* base = (char*)d_ws;
  float* fws = (float*)base;
  unsigned* upck = (unsigned*)(base + F32_TOT * sizeof(float));
  unsigned short* hws = (unsigned short*)(base + F32_TOT * sizeof(float) + U_TOT * sizeof(unsigned));
  unsigned* bar = (unsigned*)(base + F32_TOT * sizeof(float) + U_TOT * sizeof(unsigned) +
                              H_TOT * sizeof(unsigned short));
  size_t need = F32_TOT * sizeof(float) + U_TOT * sizeof(unsigned) +
                H_TOT * sizeof(unsigned short) + 8192;
  if (ws_size < need) return;

  // zero h-state + barrier slots + flags (re-runs on every graph replay)
  hipMemsetAsync(upck + UOFF_HPACK, 0, (size_t)2 * BB * HH * sizeof(unsigned), stream);
  hipMemsetAsync(bar, 0, 4096, stream);

  k_transpose_qp<<<128, 256, 0, stream>>>(Wq, Wp,
      hws + HOFF_WQTH, hws + HOFF_WQTL, hws + HOFF_WPTH, hws + HOFF_WPTL);
  k_split_w<<<1024, 256, 0, stream>>>(gw, wih, whh,
      hws + HOFF_GWH, hws + HOFF_GWL, hws + HOFF_WIHH, hws + HOFF_WIHL,
      hws + HOFF_WHHH, hws + HOFF_WHHL);
  k_wst_qin<<<2048, 256, 0, stream>>>(Ws, fws + OFF_WST, qin,
                                      hws + HOFF_QIN16);
  pe_main<<<NBLK, NTHR, 0, stream>>>(qin, pin, qmask, v, gb, bih, bhh, out,
                                     fws, upck, hws, bar);
}